// Round 1
// baseline (1116.947 us; speedup 1.0000x reference)
//
#include <hip/hip_runtime.h>
#include <stdint.h>

#define CDIM 256
#define NCODES 8192
#define MTOT 16384
#define OUT_ELEMS 4194304   // 16*256*32*32
#define BETA 0.25f

// ws layout (bytes)
#define WS_PACKED 0u        // 16384 * 8 = 131072
#define WS_ENORM 131072u    // 8192 * 4  = 32768
#define WS_ZSQ   163840u    // 16384 * 4 = 65536
#define WS_COUNTS 229376u   // 8192 * 4  = 32768
#define WS_LOSS  262144u    // 4

// ---------------- zsq: ||z_row||^2 per (b,h,w), fp32 sequential over c ----------------
__global__ void zsq_kernel(const float* __restrict__ z, float* __restrict__ zsq) {
  int blk = blockIdx.x;          // 64 blocks
  int j = threadIdx.x;
  int b = blk >> 2;
  int p = ((blk & 3) << 8) + j;  // pixel within image
  const float* zp = z + (size_t)b * (CDIM * 1024) + p;
  float acc = 0.f;
  #pragma unroll 8
  for (int c = 0; c < CDIM; ++c) {
    float v = zp[(size_t)c * 1024];
    acc += v * v;
  }
  zsq[(blk << 8) + j] = acc;
}

// ---------------- enorm: ||e_n||^2, one wave per code row ----------------
__global__ void enorm_kernel(const float* __restrict__ E, float* __restrict__ enorm) {
  int wave = threadIdx.x >> 6;
  int lane = threadIdx.x & 63;
  int n = blockIdx.x * 4 + wave;
  float4 v = reinterpret_cast<const float4*>(E + (size_t)n * CDIM)[lane];
  float s = v.x * v.x + v.y * v.y + v.z * v.z + v.w * v.w;
  #pragma unroll
  for (int off = 32; off; off >>= 1) s += __shfl_down(s, off, 64);
  if (lane == 0) enorm[n] = s;
}

// ---------------- fused distance GEMM + partial argmin ----------------
#define BM 128
#define BN 128
#define BK 32

__global__ __launch_bounds__(256, 2) void dist_kernel(
    const float* __restrict__ z, const float* __restrict__ E,
    const float* __restrict__ zsq, const float* __restrict__ enorm,
    unsigned long long* __restrict__ packed) {
  __shared__ float zs[BK][BM];
  __shared__ float es[BK][BN];
  const int t = threadIdx.x;
  const int m0 = blockIdx.x * BM;   // 128 M tiles
  const int n0 = blockIdx.y * BN;   // 64 N tiles
  const int b = m0 >> 10;
  const int p0 = m0 & 1023;

  // z staging mapping: fully coalesced, contiguous LDS writes
  const int zc = t >> 5;           // 0..7
  const int zm = (t & 31) << 2;    // 0..124
  const float* zbase = z + (size_t)b * 262144 + p0 + zm;

  // e staging: thread owns one code row, 16 consecutive c (one 64B line)
  const int en = t & 127;
  const int ec = (t >> 7) << 4;    // 0 or 16
  const float* ebase = E + (size_t)(n0 + en) * CDIM + ec;

  float4 zr[4], er[4];
  #pragma unroll
  for (int r = 0; r < 4; ++r)
    zr[r] = *(const float4*)(zbase + (size_t)(r * 8 + zc) * 1024);
  #pragma unroll
  for (int i = 0; i < 4; ++i)
    er[i] = *(const float4*)(ebase + 4 * i);

  float acc[8][8];
  #pragma unroll
  for (int a = 0; a < 8; ++a)
    #pragma unroll
    for (int bb = 0; bb < 8; ++bb) acc[a][bb] = 0.f;

  const int tx = t & 15, ty = t >> 4;

  for (int kt = 0; kt < CDIM / BK; ++kt) {
    __syncthreads();
    #pragma unroll
    for (int r = 0; r < 4; ++r)
      *(float4*)&zs[r * 8 + zc][zm] = zr[r];
    #pragma unroll
    for (int i = 0; i < 4; ++i) {
      es[ec + 4 * i + 0][en] = er[i].x;
      es[ec + 4 * i + 1][en] = er[i].y;
      es[ec + 4 * i + 2][en] = er[i].z;
      es[ec + 4 * i + 3][en] = er[i].w;
    }
    __syncthreads();
    if (kt + 1 < CDIM / BK) {
      const int c0 = (kt + 1) * BK;
      #pragma unroll
      for (int r = 0; r < 4; ++r)
        zr[r] = *(const float4*)(zbase + (size_t)(c0 + r * 8 + zc) * 1024);
      #pragma unroll
      for (int i = 0; i < 4; ++i)
        er[i] = *(const float4*)(ebase + c0 + 4 * i);
    }
    #pragma unroll 8
    for (int kk = 0; kk < BK; ++kk) {
      float4 za  = *(const float4*)&zs[kk][ty * 4];
      float4 zb4 = *(const float4*)&zs[kk][64 + ty * 4];
      float4 ea  = *(const float4*)&es[kk][tx * 4];
      float4 eb4 = *(const float4*)&es[kk][64 + tx * 4];
      float zv[8] = {za.x, za.y, za.z, za.w, zb4.x, zb4.y, zb4.z, zb4.w};
      float ev[8] = {ea.x, ea.y, ea.z, ea.w, eb4.x, eb4.y, eb4.z, eb4.w};
      #pragma unroll
      for (int a = 0; a < 8; ++a)
        #pragma unroll
        for (int bb = 0; bb < 8; ++bb)
          acc[a][bb] += zv[a] * ev[bb];
    }
  }

  // epilogue: d = fl(fl(zsq + enorm) - 2*dot), argmin with lowest-index tie-break
  #pragma unroll
  for (int a = 0; a < 8; ++a) {
    int rloc = (a < 4) ? (ty * 4 + a) : (64 + ty * 4 + (a - 4));
    float zq = zsq[m0 + rloc];
    float bestd = 3.4e38f;
    int bestn = 0;
    #pragma unroll
    for (int bb = 0; bb < 8; ++bb) {
      int nloc = (bb < 4) ? (tx * 4 + bb) : (64 + tx * 4 + (bb - 4));
      int n = n0 + nloc;
      float tt = zq + enorm[n];         // tiny enorm mostly rounds away, as in ref
      float d = tt - 2.0f * acc[a][bb]; // 2*dot exact; single final rounding
      if (d < bestd) { bestd = d; bestn = n; }
    }
    unsigned long long pk =
        ((unsigned long long)__float_as_uint(bestd) << 32) | (unsigned)bestn;
    #pragma unroll
    for (int off = 1; off < 16; off <<= 1) {
      unsigned long long other = __shfl_xor(pk, off, 16);
      if (other < pk) pk = other;
    }
    if (tx == 0) atomicMin(&packed[m0 + rloc], pk);
  }
}

// ---------------- gather z_q, write out (straight-through), loss partial ----------------
__global__ void out_kernel(const float* __restrict__ z, const float* __restrict__ E,
                           const unsigned long long* __restrict__ packed,
                           float* __restrict__ out, float* __restrict__ loss_acc) {
  int o = blockIdx.x * 256 + threadIdx.x;
  int p = o & 1023;
  int c = (o >> 10) & 255;
  int b = o >> 18;
  int m = (b << 10) | p;
  int idx = (int)(unsigned)(packed[m] & 0xffffffffull);
  float e = E[(size_t)idx * CDIM + c];
  float zv = z[o];
  float diff = e - zv;        // fl(z_q - z), same as both loss terms
  out[o] = zv + diff;         // straight-through: z + fl(z_q - z), ref rounding
  float s = diff * diff;
  #pragma unroll
  for (int off = 32; off; off >>= 1) s += __shfl_down(s, off, 64);
  __shared__ float red[4];
  int wv = threadIdx.x >> 6, lane = threadIdx.x & 63;
  if (lane == 0) red[wv] = s;
  __syncthreads();
  if (threadIdx.x == 0) atomicAdd(loss_acc, red[0] + red[1] + red[2] + red[3]);
}

// ---------------- indices output + histogram ----------------
__global__ void idx_kernel(const unsigned long long* __restrict__ packed,
                           float* __restrict__ out_idx, unsigned int* __restrict__ counts) {
  int m = blockIdx.x * 256 + threadIdx.x;
  int idx = (int)(unsigned)(packed[m] & 0xffffffffull);
  out_idx[m] = (float)idx;
  atomicAdd(&counts[idx], 1u);
}

// ---------------- loss finalize + perplexity ----------------
__global__ void scalar_kernel(const unsigned int* __restrict__ counts,
                              const float* __restrict__ loss_acc,
                              float* __restrict__ out) {
  float s = 0.f;
  for (int i = threadIdx.x; i < NCODES; i += 256) {
    float pl = (float)counts[i] * (1.0f / 16384.0f);
    s += pl * logf(pl + 1e-10f);
  }
  #pragma unroll
  for (int off = 32; off; off >>= 1) s += __shfl_down(s, off, 64);
  __shared__ float red[4];
  int wv = threadIdx.x >> 6, lane = threadIdx.x & 63;
  if (lane == 0) red[wv] = s;
  __syncthreads();
  if (threadIdx.x == 0) {
    float tot = red[0] + red[1] + red[2] + red[3];
    out[OUT_ELEMS + MTOT] = (1.0f + BETA) * loss_acc[0] * (1.0f / (float)OUT_ELEMS);
    out[OUT_ELEMS + MTOT + 1] = expf(-tot);
  }
}

extern "C" void kernel_launch(void* const* d_in, const int* in_sizes, int n_in,
                              void* d_out, int out_size, void* d_ws, size_t ws_size,
                              hipStream_t stream) {
  const float* z = (const float*)d_in[0];
  const float* E = (const float*)d_in[1];
  float* out = (float*)d_out;
  char* ws = (char*)d_ws;
  unsigned long long* packed = (unsigned long long*)(ws + WS_PACKED);
  float* enorm = (float*)(ws + WS_ENORM);
  float* zsq = (float*)(ws + WS_ZSQ);
  unsigned int* counts = (unsigned int*)(ws + WS_COUNTS);
  float* loss_acc = (float*)(ws + WS_LOSS);

  hipMemsetAsync(packed, 0xFF, MTOT * 8, stream);
  hipMemsetAsync(counts, 0, NCODES * 4 + 4, stream);  // counts + loss_acc (adjacent)

  zsq_kernel<<<64, 256, 0, stream>>>(z, zsq);
  enorm_kernel<<<NCODES / 4, 256, 0, stream>>>(E, enorm);
  dim3 g(MTOT / BM, NCODES / BN);
  dist_kernel<<<g, 256, 0, stream>>>(z, E, zsq, enorm, packed);
  out_kernel<<<OUT_ELEMS / 256, 256, 0, stream>>>(z, E, packed, out, loss_acc);
  idx_kernel<<<MTOT / 256, 256, 0, stream>>>(packed, out + OUT_ELEMS, counts);
  scalar_kernel<<<1, 256, 0, stream>>>(counts, loss_acc, out);
}

// Round 2
// 411.381 us; speedup vs baseline: 2.7151x; 2.7151x over previous
//
#include <hip/hip_runtime.h>
#include <stdint.h>

typedef unsigned long long u64;
typedef unsigned int u32;

#define CDIM 256
#define NCODES 8192
#define MTOT 16384
#define OUT_ELEMS 4194304   // 16*256*32*32
#define BETA 0.25f
#define NTILE 64            // number of 128-wide N tiles

// ws layout (bytes)
#define WS_PACKED 0u            // 16384*8 = 131072
#define WS_ENORM  131072u       // 32768
#define WS_ZSQ    163840u       // 65536
#define WS_COUNTS 229376u       // 32768
#define WS_LOSS   262144u       // 256 (only 4 used)
#define WS_ZSQ4   262400u       // 16384*4*4 = 262144
#define WS_ZB     524544u       // 16384*256*2 = 8388608
#define WS_EB     8913152u      // 8192*256*2 = 4194304
#define WS_TT2    13107456u     // 16384*64*2*8 = 16777216
#define WS_NEEDED 29884672u

typedef short bf16x8 __attribute__((ext_vector_type(8)));
typedef float f32x4 __attribute__((ext_vector_type(4)));

#define GL2LDS16(g, l) __builtin_amdgcn_global_load_lds(            \
    (const __attribute__((address_space(1))) void*)(g),             \
    (__attribute__((address_space(3))) void*)(l), 16, 0, 0)

__device__ __forceinline__ unsigned short f2bf(float f) {
  u32 u = __float_as_uint(f);
  u32 r = (u + 0x7FFFu + ((u >> 16) & 1u)) >> 16;   // RNE
  return (unsigned short)r;
}
// monotone float<->uint (handles negatives)
__device__ __forceinline__ u32 encf(float f) {
  u32 u = __float_as_uint(f);
  return u ^ (u32)(((int)u >> 31) | 0x80000000);
}
__device__ __forceinline__ float decf(u32 u) {
  u32 v = u ^ ((((int)u) >= 0) ? 0xFFFFFFFFu : 0x80000000u);
  return __uint_as_float(v);
}
__device__ __forceinline__ void top2_merge(u64& a1, u64& a2, u64 b1, u64 b2) {
  u64 lo = a1 < b1 ? a1 : b1;
  u64 mx = a1 < b1 ? b1 : a1;
  u64 cand = a1 < b1 ? a2 : b2;
  a1 = lo;
  a2 = mx < cand ? mx : cand;
}

// ---------------- convert: z NCHW->NHWC bf16 (+zsq partials), E->bf16 ----------------
__global__ void conv_kernel(const float* __restrict__ z, const float* __restrict__ E,
                            unsigned short* __restrict__ zb, unsigned short* __restrict__ eb,
                            float* __restrict__ zsq4) {
  int blk = blockIdx.x;
  int t = threadIdx.x, w = t >> 6, lane = t & 63;
  if (blk < 1024) {
    __shared__ unsigned short tz[64][66];
    __shared__ float part[4][64];
    int b = blk >> 6, rem = blk & 63;
    int ct = rem >> 4, pt = rem & 15;
    int c0 = ct << 6, p0 = pt << 6;
    const float* zp = z + ((size_t)b << 18) + ((size_t)c0 << 10) + p0;
    float sq = 0.f;
    #pragma unroll
    for (int i = 0; i < 16; ++i) {
      int cl = w + (i << 2);
      float v = zp[((size_t)cl << 10) + lane];
      sq = fmaf(v, v, sq);
      tz[cl][lane] = f2bf(v);
    }
    part[w][lane] = sq;
    __syncthreads();
    if (w == 0) {
      float s = ((part[0][lane] + part[1][lane]) + part[2][lane]) + part[3][lane];
      zsq4[(((size_t)b << 10) + p0 + lane) * 4 + ct] = s;
    }
    #pragma unroll
    for (int j = 0; j < 16; ++j) {
      int pl = w + (j << 2);
      zb[(((size_t)b << 10) + p0 + pl) * 256 + c0 + lane] = tz[lane][pl];
    }
  } else {
    int e4 = blk - 1024;
    size_t base = ((size_t)e4 << 11) + ((size_t)t << 3);
    float4 v0 = *(const float4*)&E[base];
    float4 v1 = *(const float4*)&E[base + 4];
    ushort4 o0 = { f2bf(v0.x), f2bf(v0.y), f2bf(v0.z), f2bf(v0.w) };
    ushort4 o1 = { f2bf(v1.x), f2bf(v1.y), f2bf(v1.z), f2bf(v1.w) };
    *(ushort4*)&eb[base] = o0;
    *(ushort4*)&eb[base + 4] = o1;
  }
}

__global__ void zsqfin_kernel(const float* __restrict__ zsq4, float* __restrict__ zsq) {
  int m = blockIdx.x * 256 + threadIdx.x;
  float4 v = *(const float4*)&zsq4[(size_t)m * 4];
  zsq[m] = ((v.x + v.y) + v.z) + v.w;
}

// ---------------- enorm ----------------
__global__ void enorm_kernel(const float* __restrict__ E, float* __restrict__ enorm) {
  int wave = threadIdx.x >> 6;
  int lane = threadIdx.x & 63;
  int n = blockIdx.x * 4 + wave;
  float4 v = reinterpret_cast<const float4*>(E + (size_t)n * CDIM)[lane];
  float s = v.x * v.x + v.y * v.y + v.z * v.z + v.w * v.w;
  #pragma unroll
  for (int off = 32; off; off >>= 1) s += __shfl_down(s, off, 64);
  if (lane == 0) enorm[n] = s;
}

// ---------------- K1: bf16 MFMA GEMM + per-row per-tile top-2 ----------------
__global__ __launch_bounds__(256) void gemm_kernel(
    const unsigned short* __restrict__ zb, const unsigned short* __restrict__ eb,
    u64* __restrict__ tt2) {
  __shared__ unsigned short As[128 * 32];
  __shared__ unsigned short Bs[128 * 32];
  const int t = threadIdx.x;
  const int w = t >> 6, lane = t & 63;
  const int m0 = blockIdx.x << 7, n0 = blockIdx.y << 7;
  const int r16 = lane & 15, kg = lane >> 4;

  f32x4 acc[2][8];
  #pragma unroll
  for (int i = 0; i < 2; ++i)
    #pragma unroll
    for (int j = 0; j < 8; ++j) acc[i][j] = (f32x4)0.f;

  const unsigned short* zsrc = zb + (((size_t)m0 + (t >> 2)) << 8) + ((t & 3) << 3);
  const unsigned short* esrc = eb + (((size_t)n0 + (t >> 2)) << 8) + ((t & 3) << 3);

  for (int kt = 0; kt < 8; ++kt) {
    if (kt) __syncthreads();
    const int ko = kt << 5;
    #pragma unroll
    for (int j = 0; j < 2; ++j) {
      GL2LDS16(zsrc + (j << 14) + ko, (char*)As + (j << 12) + t * 16);
      GL2LDS16(esrc + (j << 14) + ko, (char*)Bs + (j << 12) + t * 16);
    }
    __syncthreads();
    bf16x8 af[2], bq[8];
    #pragma unroll
    for (int mi = 0; mi < 2; ++mi)
      af[mi] = *(const bf16x8*)&As[(((w << 1) + mi) * 16 + r16) * 32 + (kg << 3)];
    #pragma unroll
    for (int ni = 0; ni < 8; ++ni)
      bq[ni] = *(const bf16x8*)&Bs[(ni * 16 + r16) * 32 + (kg << 3)];
    #pragma unroll
    for (int mi = 0; mi < 2; ++mi)
      #pragma unroll
      for (int ni = 0; ni < 8; ++ni)
        acc[mi][ni] = __builtin_amdgcn_mfma_f32_16x16x32_bf16(af[mi], bq[ni], acc[mi][ni], 0, 0, 0);
  }

  // epilogue: approx key = -dot (ordering of distances), top-2 per row over 128 cols
  #pragma unroll
  for (int mi = 0; mi < 2; ++mi) {
    #pragma unroll
    for (int reg = 0; reg < 4; ++reg) {
      int row = (w << 5) + (mi << 4) + (kg << 2) + reg;
      u64 a1 = ~0ull, a2 = ~0ull;
      #pragma unroll
      for (int ni = 0; ni < 8; ++ni) {
        float d = -acc[mi][ni][reg];
        u64 k = ((u64)encf(d) << 32) | (u32)(n0 + (ni << 4) + r16);
        if (k < a1) { a2 = a1; a1 = k; } else if (k < a2) a2 = k;
      }
      #pragma unroll
      for (int off = 1; off < 16; off <<= 1) {
        u64 b1 = __shfl_xor(a1, off, 16);
        u64 b2 = __shfl_xor(a2, off, 16);
        top2_merge(a1, a2, b1, b2);
      }
      if (r16 == 0) {
        size_t o = ((size_t)(m0 + row) * NTILE + blockIdx.y) * 2;
        tt2[o] = a1;
        tt2[o + 1] = a2;
      }
    }
  }
}

// ---------------- K2: exact fp32 refinement of candidates ----------------
__global__ __launch_bounds__(256) void refine_kernel(
    const float* __restrict__ z, const float* __restrict__ E,
    const float* __restrict__ zsq, const float* __restrict__ enorm,
    const u64* __restrict__ tt2, u64* __restrict__ packed) {
  const int t = threadIdx.x, w = t >> 6, lane = t & 63;
  const int m = (blockIdx.x << 2) + w;
  const int b = m >> 10, p = m & 1023;
  const u64* base = tt2 + (size_t)m * 128;
  u64 c0 = base[lane * 2], c1 = base[lane * 2 + 1];
  u64 kmin = c0 < c1 ? c0 : c1;
  #pragma unroll
  for (int off = 1; off < 64; off <<= 1) {
    u64 o = __shfl_xor(kmin, off, 64);
    if (o < kmin) kmin = o;
  }
  float thr = decf((u32)(kmin >> 32)) + 1e-4f;
  const float* zbp = z + ((size_t)b << 18) + p;
  float zr0 = zbp[(size_t)(lane * 4 + 0) << 10];
  float zr1 = zbp[(size_t)(lane * 4 + 1) << 10];
  float zr2 = zbp[(size_t)(lane * 4 + 2) << 10];
  float zr3 = zbp[(size_t)(lane * 4 + 3) << 10];
  float zsqm = zsq[m];
  u64 best = ~0ull;
  #pragma unroll
  for (int s = 0; s < 2; ++s) {
    u64 ck = s ? c1 : c0;
    bool pass = decf((u32)(ck >> 32)) <= thr;
    u64 mask = __ballot(pass);
    while (mask) {
      int src = __ffsll((unsigned long long)mask) - 1;
      mask &= mask - 1;
      u64 key = __shfl(ck, src, 64);
      int idx = (int)(u32)key;
      const float4 e4 = *(const float4*)&E[(size_t)idx * CDIM + lane * 4];
      float pa = zr0 * e4.x;
      pa = fmaf(zr1, e4.y, pa);
      pa = fmaf(zr2, e4.z, pa);
      pa = fmaf(zr3, e4.w, pa);
      #pragma unroll
      for (int off = 1; off < 64; off <<= 1) pa += __shfl_xor(pa, off, 64);
      float ttv = zsqm + enorm[idx];
      float d = ttv - 2.0f * pa;
      u64 k2 = ((u64)__float_as_uint(d) << 32) | (u32)idx;
      if (k2 < best) best = k2;
    }
  }
  if (lane == 0) packed[m] = best;
}

// ---------------- fallback exact fp32 path (round-1) ----------------
__global__ void zsq_kernel(const float* __restrict__ z, float* __restrict__ zsq) {
  int blk = blockIdx.x;
  int j = threadIdx.x;
  int b = blk >> 2;
  int p = ((blk & 3) << 8) + j;
  const float* zp = z + (size_t)b * (CDIM * 1024) + p;
  float acc = 0.f;
  #pragma unroll 8
  for (int c = 0; c < CDIM; ++c) {
    float v = zp[(size_t)c * 1024];
    acc += v * v;
  }
  zsq[(blk << 8) + j] = acc;
}

#define BM 128
#define BN 128
#define BK 32
__global__ __launch_bounds__(256, 2) void dist_kernel(
    const float* __restrict__ z, const float* __restrict__ E,
    const float* __restrict__ zsq, const float* __restrict__ enorm,
    unsigned long long* __restrict__ packed) {
  __shared__ float zs[BK][BM];
  __shared__ float es[BK][BN];
  const int t = threadIdx.x;
  const int m0 = blockIdx.x * BM;
  const int n0 = blockIdx.y * BN;
  const int b = m0 >> 10;
  const int p0 = m0 & 1023;
  const int zc = t >> 5;
  const int zm = (t & 31) << 2;
  const float* zbase = z + (size_t)b * 262144 + p0 + zm;
  const int en = t & 127;
  const int ec = (t >> 7) << 4;
  const float* ebase = E + (size_t)(n0 + en) * CDIM + ec;
  float4 zr[4], er[4];
  #pragma unroll
  for (int r = 0; r < 4; ++r)
    zr[r] = *(const float4*)(zbase + (size_t)(r * 8 + zc) * 1024);
  #pragma unroll
  for (int i = 0; i < 4; ++i)
    er[i] = *(const float4*)(ebase + 4 * i);
  float acc[8][8];
  #pragma unroll
  for (int a = 0; a < 8; ++a)
    #pragma unroll
    for (int bb = 0; bb < 8; ++bb) acc[a][bb] = 0.f;
  const int tx = t & 15, ty = t >> 4;
  for (int kt = 0; kt < CDIM / BK; ++kt) {
    __syncthreads();
    #pragma unroll
    for (int r = 0; r < 4; ++r)
      *(float4*)&zs[r * 8 + zc][zm] = zr[r];
    #pragma unroll
    for (int i = 0; i < 4; ++i) {
      es[ec + 4 * i + 0][en] = er[i].x;
      es[ec + 4 * i + 1][en] = er[i].y;
      es[ec + 4 * i + 2][en] = er[i].z;
      es[ec + 4 * i + 3][en] = er[i].w;
    }
    __syncthreads();
    if (kt + 1 < CDIM / BK) {
      const int c0 = (kt + 1) * BK;
      #pragma unroll
      for (int r = 0; r < 4; ++r)
        zr[r] = *(const float4*)(zbase + (size_t)(c0 + r * 8 + zc) * 1024);
      #pragma unroll
      for (int i = 0; i < 4; ++i)
        er[i] = *(const float4*)(ebase + c0 + 4 * i);
    }
    #pragma unroll 8
    for (int kk = 0; kk < BK; ++kk) {
      float4 za = *(const float4*)&zs[kk][ty * 4];
      float4 zb4 = *(const float4*)&zs[kk][64 + ty * 4];
      float4 ea = *(const float4*)&es[kk][tx * 4];
      float4 eb4 = *(const float4*)&es[kk][64 + tx * 4];
      float zv[8] = {za.x, za.y, za.z, za.w, zb4.x, zb4.y, zb4.z, zb4.w};
      float ev[8] = {ea.x, ea.y, ea.z, ea.w, eb4.x, eb4.y, eb4.z, eb4.w};
      #pragma unroll
      for (int a = 0; a < 8; ++a)
        #pragma unroll
        for (int bb = 0; bb < 8; ++bb)
          acc[a][bb] += zv[a] * ev[bb];
    }
  }
  #pragma unroll
  for (int a = 0; a < 8; ++a) {
    int rloc = (a < 4) ? (ty * 4 + a) : (64 + ty * 4 + (a - 4));
    float zq = zsq[m0 + rloc];
    float bestd = 3.4e38f;
    int bestn = 0;
    #pragma unroll
    for (int bb = 0; bb < 8; ++bb) {
      int nloc = (bb < 4) ? (tx * 4 + bb) : (64 + tx * 4 + (bb - 4));
      int n = n0 + nloc;
      float ttv = zq + enorm[n];
      float d = ttv - 2.0f * acc[a][bb];
      if (d < bestd) { bestd = d; bestn = n; }
    }
    unsigned long long pk =
        ((unsigned long long)__float_as_uint(bestd) << 32) | (unsigned)bestn;
    #pragma unroll
    for (int off = 1; off < 16; off <<= 1) {
      unsigned long long other = __shfl_xor(pk, off, 16);
      if (other < pk) pk = other;
    }
    if (tx == 0) atomicMin(&packed[m0 + rloc], pk);
  }
}

// ---------------- gather z_q, write out, loss partial ----------------
__global__ void out_kernel(const float* __restrict__ z, const float* __restrict__ E,
                           const unsigned long long* __restrict__ packed,
                           float* __restrict__ out, float* __restrict__ loss_acc) {
  int o = blockIdx.x * 256 + threadIdx.x;
  int p = o & 1023;
  int c = (o >> 10) & 255;
  int b = o >> 18;
  int m = (b << 10) | p;
  int idx = (int)(unsigned)(packed[m] & 0xffffffffull);
  float e = E[(size_t)idx * CDIM + c];
  float zv = z[o];
  float diff = e - zv;
  out[o] = zv + diff;
  float s = diff * diff;
  #pragma unroll
  for (int off = 32; off; off >>= 1) s += __shfl_down(s, off, 64);
  __shared__ float red[4];
  int wv = threadIdx.x >> 6, lane = threadIdx.x & 63;
  if (lane == 0) red[wv] = s;
  __syncthreads();
  if (threadIdx.x == 0) atomicAdd(loss_acc, red[0] + red[1] + red[2] + red[3]);
}

__global__ void idx_kernel(const unsigned long long* __restrict__ packed,
                           float* __restrict__ out_idx, unsigned int* __restrict__ counts) {
  int m = blockIdx.x * 256 + threadIdx.x;
  int idx = (int)(unsigned)(packed[m] & 0xffffffffull);
  out_idx[m] = (float)idx;
  atomicAdd(&counts[idx], 1u);
}

__global__ void scalar_kernel(const unsigned int* __restrict__ counts,
                              const float* __restrict__ loss_acc,
                              float* __restrict__ out) {
  float s = 0.f;
  for (int i = threadIdx.x; i < NCODES; i += 256) {
    float pl = (float)counts[i] * (1.0f / 16384.0f);
    s += pl * logf(pl + 1e-10f);
  }
  #pragma unroll
  for (int off = 32; off; off >>= 1) s += __shfl_down(s, off, 64);
  __shared__ float red[4];
  int wv = threadIdx.x >> 6, lane = threadIdx.x & 63;
  if (lane == 0) red[wv] = s;
  __syncthreads();
  if (threadIdx.x == 0) {
    float tot = red[0] + red[1] + red[2] + red[3];
    out[OUT_ELEMS + MTOT] = (1.0f + BETA) * loss_acc[0] * (1.0f / (float)OUT_ELEMS);
    out[OUT_ELEMS + MTOT + 1] = expf(-tot);
  }
}

extern "C" void kernel_launch(void* const* d_in, const int* in_sizes, int n_in,
                              void* d_out, int out_size, void* d_ws, size_t ws_size,
                              hipStream_t stream) {
  const float* z = (const float*)d_in[0];
  const float* E = (const float*)d_in[1];
  float* out = (float*)d_out;
  char* ws = (char*)d_ws;
  u64* packed = (u64*)(ws + WS_PACKED);
  float* enorm = (float*)(ws + WS_ENORM);
  float* zsq = (float*)(ws + WS_ZSQ);
  u32* counts = (u32*)(ws + WS_COUNTS);
  float* loss_acc = (float*)(ws + WS_LOSS);

  hipMemsetAsync(counts, 0, 32768 + 256, stream);  // counts + loss_acc
  enorm_kernel<<<NCODES / 4, 256, 0, stream>>>(E, enorm);

  if (ws_size >= WS_NEEDED) {
    unsigned short* zb = (unsigned short*)(ws + WS_ZB);
    unsigned short* ebuf = (unsigned short*)(ws + WS_EB);
    u64* tt2 = (u64*)(ws + WS_TT2);
    float* zsq4 = (float*)(ws + WS_ZSQ4);
    conv_kernel<<<2048, 256, 0, stream>>>(z, E, zb, ebuf, zsq4);
    zsqfin_kernel<<<64, 256, 0, stream>>>(zsq4, zsq);
    dim3 g(MTOT / 128, NCODES / 128);
    gemm_kernel<<<g, 256, 0, stream>>>(zb, ebuf, tt2);
    refine_kernel<<<MTOT / 4, 256, 0, stream>>>(z, E, zsq, enorm, tt2, packed);
  } else {
    hipMemsetAsync(packed, 0xFF, MTOT * 8, stream);
    zsq_kernel<<<64, 256, 0, stream>>>(z, zsq);
    dim3 g(MTOT / BM, NCODES / BN);
    dist_kernel<<<g, 256, 0, stream>>>(z, E, zsq, enorm, packed);
  }

  out_kernel<<<OUT_ELEMS / 256, 256, 0, stream>>>(z, E, packed, out, loss_acc);
  idx_kernel<<<MTOT / 256, 256, 0, stream>>>(packed, out + OUT_ELEMS, counts);
  scalar_kernel<<<1, 256, 0, stream>>>(counts, loss_acc, out);
}

// Round 3
// 211.798 us; speedup vs baseline: 5.2736x; 1.9423x over previous
//
#include <hip/hip_runtime.h>
#include <stdint.h>

typedef unsigned long long u64;
typedef unsigned int u32;

#define CDIM 256
#define NCODES 8192
#define MTOT 16384
#define OUT_ELEMS 4194304   // 16*256*32*32
#define BETA 0.25f
#define NTILE 64            // number of 128-wide N tiles

// ws layout (bytes)
#define WS_PACKED 0u            // 16384*8 = 131072
#define WS_ENORM  131072u       // 32768
#define WS_ZSQ    163840u       // 65536
#define WS_COUNTS 229376u       // 32768
#define WS_LOSS   262144u       // 256 (only 4 used)
#define WS_ZSQ4   262400u       // 16384*4*4 = 262144
#define WS_ZB     524544u       // 16384*256*2 = 8388608
#define WS_EB     8913152u      // 8192*256*2 = 4194304
#define WS_TT2    13107456u     // 16384*64*2*8 = 16777216
#define WS_NEEDED 29884672u

typedef short bf16x8 __attribute__((ext_vector_type(8)));
typedef float f32x4 __attribute__((ext_vector_type(4)));

#define GL2LDS16(g, l) __builtin_amdgcn_global_load_lds(            \
    (const __attribute__((address_space(1))) void*)(g),             \
    (__attribute__((address_space(3))) void*)(l), 16, 0, 0)

__device__ __forceinline__ unsigned short f2bf(float f) {
  u32 u = __float_as_uint(f);
  u32 r = (u + 0x7FFFu + ((u >> 16) & 1u)) >> 16;   // RNE
  return (unsigned short)r;
}
// monotone float<->uint (handles negatives)
__device__ __forceinline__ u32 encf(float f) {
  u32 u = __float_as_uint(f);
  return u ^ (u32)(((int)u >> 31) | 0x80000000);
}
__device__ __forceinline__ float decf(u32 u) {
  u32 v = u ^ ((((int)u) >= 0) ? 0xFFFFFFFFu : 0x80000000u);
  return __uint_as_float(v);
}
__device__ __forceinline__ void top2_merge(u64& a1, u64& a2, u64 b1, u64 b2) {
  u64 lo = a1 < b1 ? a1 : b1;
  u64 mx = a1 < b1 ? b1 : a1;
  u64 cand = a1 < b1 ? a2 : b2;
  a1 = lo;
  a2 = mx < cand ? mx : cand;
}

// ---------------- convert: z NCHW->NHWC bf16 (+zsq partials), E->bf16 ----------------
__global__ void conv_kernel(const float* __restrict__ z, const float* __restrict__ E,
                            unsigned short* __restrict__ zb, unsigned short* __restrict__ eb,
                            float* __restrict__ zsq4) {
  int blk = blockIdx.x;
  int t = threadIdx.x, w = t >> 6, lane = t & 63;
  if (blk < 1024) {
    __shared__ unsigned short tz[64][66];
    __shared__ float part[4][64];
    int b = blk >> 6, rem = blk & 63;
    int ct = rem >> 4, pt = rem & 15;
    int c0 = ct << 6, p0 = pt << 6;
    const float* zp = z + ((size_t)b << 18) + ((size_t)c0 << 10) + p0;
    float sq = 0.f;
    #pragma unroll
    for (int i = 0; i < 16; ++i) {
      int cl = w + (i << 2);
      float v = zp[((size_t)cl << 10) + lane];
      sq = fmaf(v, v, sq);
      tz[cl][lane] = f2bf(v);
    }
    part[w][lane] = sq;
    __syncthreads();
    if (w == 0) {
      float s = ((part[0][lane] + part[1][lane]) + part[2][lane]) + part[3][lane];
      zsq4[(((size_t)b << 10) + p0 + lane) * 4 + ct] = s;
    }
    #pragma unroll
    for (int j = 0; j < 16; ++j) {
      int pl = w + (j << 2);
      zb[(((size_t)b << 10) + p0 + pl) * 256 + c0 + lane] = tz[lane][pl];
    }
  } else {
    int e4 = blk - 1024;
    size_t base = ((size_t)e4 << 11) + ((size_t)t << 3);
    float4 v0 = *(const float4*)&E[base];
    float4 v1 = *(const float4*)&E[base + 4];
    ushort4 o0 = { f2bf(v0.x), f2bf(v0.y), f2bf(v0.z), f2bf(v0.w) };
    ushort4 o1 = { f2bf(v1.x), f2bf(v1.y), f2bf(v1.z), f2bf(v1.w) };
    *(ushort4*)&eb[base] = o0;
    *(ushort4*)&eb[base + 4] = o1;
  }
}

__global__ void zsqfin_kernel(const float* __restrict__ zsq4, float* __restrict__ zsq) {
  int m = blockIdx.x * 256 + threadIdx.x;
  float4 v = *(const float4*)&zsq4[(size_t)m * 4];
  zsq[m] = ((v.x + v.y) + v.z) + v.w;
}

// ---------------- enorm ----------------
__global__ void enorm_kernel(const float* __restrict__ E, float* __restrict__ enorm) {
  int wave = threadIdx.x >> 6;
  int lane = threadIdx.x & 63;
  int n = blockIdx.x * 4 + wave;
  float4 v = reinterpret_cast<const float4*>(E + (size_t)n * CDIM)[lane];
  float s = v.x * v.x + v.y * v.y + v.z * v.z + v.w * v.w;
  #pragma unroll
  for (int off = 32; off; off >>= 1) s += __shfl_down(s, off, 64);
  if (lane == 0) enorm[n] = s;
}

// ---------------- K1: bf16 MFMA GEMM + per-row per-tile top-2 ----------------
__global__ __launch_bounds__(256) void gemm_kernel(
    const unsigned short* __restrict__ zb, const unsigned short* __restrict__ eb,
    u64* __restrict__ tt2) {
  __shared__ unsigned short As[128 * 32];
  __shared__ unsigned short Bs[128 * 32];
  const int t = threadIdx.x;
  const int w = t >> 6, lane = t & 63;
  const int m0 = blockIdx.x << 7, n0 = blockIdx.y << 7;
  const int r16 = lane & 15, kg = lane >> 4;

  f32x4 acc[2][8];
  #pragma unroll
  for (int i = 0; i < 2; ++i)
    #pragma unroll
    for (int j = 0; j < 8; ++j) acc[i][j] = (f32x4)0.f;

  const unsigned short* zsrc = zb + (((size_t)m0 + (t >> 2)) << 8) + ((t & 3) << 3);
  const unsigned short* esrc = eb + (((size_t)n0 + (t >> 2)) << 8) + ((t & 3) << 3);

  for (int kt = 0; kt < 8; ++kt) {
    if (kt) __syncthreads();
    const int ko = kt << 5;
    #pragma unroll
    for (int j = 0; j < 2; ++j) {
      GL2LDS16(zsrc + (j << 14) + ko, (char*)As + (j << 12) + t * 16);
      GL2LDS16(esrc + (j << 14) + ko, (char*)Bs + (j << 12) + t * 16);
    }
    __syncthreads();
    bf16x8 af[2], bq[8];
    #pragma unroll
    for (int mi = 0; mi < 2; ++mi)
      af[mi] = *(const bf16x8*)&As[(((w << 1) + mi) * 16 + r16) * 32 + (kg << 3)];
    #pragma unroll
    for (int ni = 0; ni < 8; ++ni)
      bq[ni] = *(const bf16x8*)&Bs[(ni * 16 + r16) * 32 + (kg << 3)];
    #pragma unroll
    for (int mi = 0; mi < 2; ++mi)
      #pragma unroll
      for (int ni = 0; ni < 8; ++ni)
        acc[mi][ni] = __builtin_amdgcn_mfma_f32_16x16x32_bf16(af[mi], bq[ni], acc[mi][ni], 0, 0, 0);
  }

  // epilogue: approx key = -dot (ordering of distances), top-2 per row over 128 cols
  #pragma unroll
  for (int mi = 0; mi < 2; ++mi) {
    #pragma unroll
    for (int reg = 0; reg < 4; ++reg) {
      int row = (w << 5) + (mi << 4) + (kg << 2) + reg;
      u64 a1 = ~0ull, a2 = ~0ull;
      #pragma unroll
      for (int ni = 0; ni < 8; ++ni) {
        float d = -acc[mi][ni][reg];
        u64 k = ((u64)encf(d) << 32) | (u32)(n0 + (ni << 4) + r16);
        if (k < a1) { a2 = a1; a1 = k; } else if (k < a2) a2 = k;
      }
      #pragma unroll
      for (int off = 1; off < 16; off <<= 1) {
        u64 b1 = __shfl_xor(a1, off, 16);
        u64 b2 = __shfl_xor(a2, off, 16);
        top2_merge(a1, a2, b1, b2);
      }
      if (r16 == 0) {
        size_t o = ((size_t)(m0 + row) * NTILE + blockIdx.y) * 2;
        tt2[o] = a1;
        tt2[o + 1] = a2;
      }
    }
  }
}

// ---------------- K2: exact fp32 refinement of candidates ----------------
__global__ __launch_bounds__(256) void refine_kernel(
    const float* __restrict__ z, const float* __restrict__ E,
    const float* __restrict__ zsq, const float* __restrict__ enorm,
    const u64* __restrict__ tt2, u64* __restrict__ packed) {
  const int t = threadIdx.x, w = t >> 6, lane = t & 63;
  const int m = (blockIdx.x << 2) + w;
  const int b = m >> 10, p = m & 1023;
  const u64* base = tt2 + (size_t)m * 128;
  u64 c0 = base[lane * 2], c1 = base[lane * 2 + 1];
  u64 kmin = c0 < c1 ? c0 : c1;
  #pragma unroll
  for (int off = 1; off < 64; off <<= 1) {
    u64 o = __shfl_xor(kmin, off, 64);
    if (o < kmin) kmin = o;
  }
  float thr = decf((u32)(kmin >> 32)) + 1e-4f;
  const float* zbp = z + ((size_t)b << 18) + p;
  float zr0 = zbp[(size_t)(lane * 4 + 0) << 10];
  float zr1 = zbp[(size_t)(lane * 4 + 1) << 10];
  float zr2 = zbp[(size_t)(lane * 4 + 2) << 10];
  float zr3 = zbp[(size_t)(lane * 4 + 3) << 10];
  float zsqm = zsq[m];
  u64 best = ~0ull;
  #pragma unroll
  for (int s = 0; s < 2; ++s) {
    u64 ck = s ? c1 : c0;
    bool pass = decf((u32)(ck >> 32)) <= thr;
    u64 mask = __ballot(pass);
    while (mask) {
      int src = __ffsll((unsigned long long)mask) - 1;
      mask &= mask - 1;
      u64 key = __shfl(ck, src, 64);
      int idx = (int)(u32)key;
      const float4 e4 = *(const float4*)&E[(size_t)idx * CDIM + lane * 4];
      float pa = zr0 * e4.x;
      pa = fmaf(zr1, e4.y, pa);
      pa = fmaf(zr2, e4.z, pa);
      pa = fmaf(zr3, e4.w, pa);
      #pragma unroll
      for (int off = 1; off < 64; off <<= 1) pa += __shfl_xor(pa, off, 64);
      float ttv = zsqm + enorm[idx];
      float d = ttv - 2.0f * pa;
      u64 k2 = ((u64)__float_as_uint(d) << 32) | (u32)idx;
      if (k2 < best) best = k2;
    }
  }
  if (lane == 0) packed[m] = best;
}

// ---------------- fallback exact fp32 path (round-1) ----------------
__global__ void zsq_kernel(const float* __restrict__ z, float* __restrict__ zsq) {
  int blk = blockIdx.x;
  int j = threadIdx.x;
  int b = blk >> 2;
  int p = ((blk & 3) << 8) + j;
  const float* zp = z + (size_t)b * (CDIM * 1024) + p;
  float acc = 0.f;
  #pragma unroll 8
  for (int c = 0; c < CDIM; ++c) {
    float v = zp[(size_t)c * 1024];
    acc += v * v;
  }
  zsq[(blk << 8) + j] = acc;
}

#define BM 128
#define BN 128
#define BK 32
__global__ __launch_bounds__(256, 2) void dist_kernel(
    const float* __restrict__ z, const float* __restrict__ E,
    const float* __restrict__ zsq, const float* __restrict__ enorm,
    unsigned long long* __restrict__ packed) {
  __shared__ float zs[BK][BM];
  __shared__ float es[BK][BN];
  const int t = threadIdx.x;
  const int m0 = blockIdx.x * BM;
  const int n0 = blockIdx.y * BN;
  const int b = m0 >> 10;
  const int p0 = m0 & 1023;
  const int zc = t >> 5;
  const int zm = (t & 31) << 2;
  const float* zbase = z + (size_t)b * 262144 + p0 + zm;
  const int en = t & 127;
  const int ec = (t >> 7) << 4;
  const float* ebase = E + (size_t)(n0 + en) * CDIM + ec;
  float4 zr[4], er[4];
  #pragma unroll
  for (int r = 0; r < 4; ++r)
    zr[r] = *(const float4*)(zbase + (size_t)(r * 8 + zc) * 1024);
  #pragma unroll
  for (int i = 0; i < 4; ++i)
    er[i] = *(const float4*)(ebase + 4 * i);
  float acc[8][8];
  #pragma unroll
  for (int a = 0; a < 8; ++a)
    #pragma unroll
    for (int bb = 0; bb < 8; ++bb) acc[a][bb] = 0.f;
  const int tx = t & 15, ty = t >> 4;
  for (int kt = 0; kt < CDIM / BK; ++kt) {
    __syncthreads();
    #pragma unroll
    for (int r = 0; r < 4; ++r)
      *(float4*)&zs[r * 8 + zc][zm] = zr[r];
    #pragma unroll
    for (int i = 0; i < 4; ++i) {
      es[ec + 4 * i + 0][en] = er[i].x;
      es[ec + 4 * i + 1][en] = er[i].y;
      es[ec + 4 * i + 2][en] = er[i].z;
      es[ec + 4 * i + 3][en] = er[i].w;
    }
    __syncthreads();
    if (kt + 1 < CDIM / BK) {
      const int c0 = (kt + 1) * BK;
      #pragma unroll
      for (int r = 0; r < 4; ++r)
        zr[r] = *(const float4*)(zbase + (size_t)(c0 + r * 8 + zc) * 1024);
      #pragma unroll
      for (int i = 0; i < 4; ++i)
        er[i] = *(const float4*)(ebase + c0 + 4 * i);
    }
    #pragma unroll 8
    for (int kk = 0; kk < BK; ++kk) {
      float4 za = *(const float4*)&zs[kk][ty * 4];
      float4 zb4 = *(const float4*)&zs[kk][64 + ty * 4];
      float4 ea = *(const float4*)&es[kk][tx * 4];
      float4 eb4 = *(const float4*)&es[kk][64 + tx * 4];
      float zv[8] = {za.x, za.y, za.z, za.w, zb4.x, zb4.y, zb4.z, zb4.w};
      float ev[8] = {ea.x, ea.y, ea.z, ea.w, eb4.x, eb4.y, eb4.z, eb4.w};
      #pragma unroll
      for (int a = 0; a < 8; ++a)
        #pragma unroll
        for (int bb = 0; bb < 8; ++bb)
          acc[a][bb] += zv[a] * ev[bb];
    }
  }
  #pragma unroll
  for (int a = 0; a < 8; ++a) {
    int rloc = (a < 4) ? (ty * 4 + a) : (64 + ty * 4 + (a - 4));
    float zq = zsq[m0 + rloc];
    float bestd = 3.4e38f;
    int bestn = 0;
    #pragma unroll
    for (int bb = 0; bb < 8; ++bb) {
      int nloc = (bb < 4) ? (tx * 4 + bb) : (64 + tx * 4 + (bb - 4));
      int n = n0 + nloc;
      float ttv = zq + enorm[n];
      float d = ttv - 2.0f * acc[a][bb];
      if (d < bestd) { bestd = d; bestn = n; }
    }
    unsigned long long pk =
        ((unsigned long long)__float_as_uint(bestd) << 32) | (unsigned)bestn;
    #pragma unroll
    for (int off = 1; off < 16; off <<= 1) {
      unsigned long long other = __shfl_xor(pk, off, 16);
      if (other < pk) pk = other;
    }
    if (tx == 0) atomicMin(&packed[m0 + rloc], pk);
  }
}

// ---------------- gather z_q via LDS transpose, write out (ST), loss partial ----------------
// Each block: 32 pixels (one b). Stage the 32 selected E rows coalesced into
// padded LDS [32][257], then stream z/out NCHW coalesced (two 128B segs/wave).
__global__ __launch_bounds__(256) void out_kernel(
    const float* __restrict__ z, const float* __restrict__ E,
    const u64* __restrict__ packed,
    float* __restrict__ out, float* __restrict__ loss_acc) {
  __shared__ float es[32][257];
  const int t = threadIdx.x, w = t >> 6, lane = t & 63;
  const int m0 = blockIdx.x << 5;          // 512 blocks
  const int b = m0 >> 10, p0 = m0 & 1023;

  #pragma unroll
  for (int i = 0; i < 8; ++i) {
    int pl = (w << 3) + i;
    int idx = (int)(u32)(packed[m0 + pl] & 0xffffffffull);
    float4 v = *(const float4*)&E[((size_t)idx << 8) + (lane << 2)];
    es[pl][(lane << 2) + 0] = v.x;
    es[pl][(lane << 2) + 1] = v.y;
    es[pl][(lane << 2) + 2] = v.z;
    es[pl][(lane << 2) + 3] = v.w;
  }
  __syncthreads();

  const int pp = lane & 31, chi = lane >> 5;
  const size_t gbase = ((size_t)b << 18) + p0 + pp;
  float s = 0.f;
  #pragma unroll 8
  for (int i = 0; i < 32; ++i) {
    int c = (i << 3) + (w << 1) + chi;
    float zv = z[gbase + ((size_t)c << 10)];
    float e = es[pp][c];
    float diff = e - zv;
    out[gbase + ((size_t)c << 10)] = zv + diff;
    s = fmaf(diff, diff, s);
  }
  #pragma unroll
  for (int off = 32; off; off >>= 1) s += __shfl_down(s, off, 64);
  __shared__ float red[4];
  if (lane == 0) red[w] = s;
  __syncthreads();
  if (t == 0) atomicAdd(loss_acc, red[0] + red[1] + red[2] + red[3]);
}

__global__ void idx_kernel(const unsigned long long* __restrict__ packed,
                           float* __restrict__ out_idx, unsigned int* __restrict__ counts) {
  int m = blockIdx.x * 256 + threadIdx.x;
  int idx = (int)(unsigned)(packed[m] & 0xffffffffull);
  out_idx[m] = (float)idx;
  atomicAdd(&counts[idx], 1u);
}

__global__ void scalar_kernel(const unsigned int* __restrict__ counts,
                              const float* __restrict__ loss_acc,
                              float* __restrict__ out) {
  float s = 0.f;
  for (int i = threadIdx.x; i < NCODES; i += 256) {
    float pl = (float)counts[i] * (1.0f / 16384.0f);
    s += pl * logf(pl + 1e-10f);
  }
  #pragma unroll
  for (int off = 32; off; off >>= 1) s += __shfl_down(s, off, 64);
  __shared__ float red[4];
  int wv = threadIdx.x >> 6, lane = threadIdx.x & 63;
  if (lane == 0) red[wv] = s;
  __syncthreads();
  if (threadIdx.x == 0) {
    float tot = red[0] + red[1] + red[2] + red[3];
    out[OUT_ELEMS + MTOT] = (1.0f + BETA) * loss_acc[0] * (1.0f / (float)OUT_ELEMS);
    out[OUT_ELEMS + MTOT + 1] = expf(-tot);
  }
}

extern "C" void kernel_launch(void* const* d_in, const int* in_sizes, int n_in,
                              void* d_out, int out_size, void* d_ws, size_t ws_size,
                              hipStream_t stream) {
  const float* z = (const float*)d_in[0];
  const float* E = (const float*)d_in[1];
  float* out = (float*)d_out;
  char* ws = (char*)d_ws;
  u64* packed = (u64*)(ws + WS_PACKED);
  float* enorm = (float*)(ws + WS_ENORM);
  float* zsq = (float*)(ws + WS_ZSQ);
  u32* counts = (u32*)(ws + WS_COUNTS);
  float* loss_acc = (float*)(ws + WS_LOSS);

  hipMemsetAsync(counts, 0, 32768 + 256, stream);  // counts + loss_acc
  enorm_kernel<<<NCODES / 4, 256, 0, stream>>>(E, enorm);

  if (ws_size >= WS_NEEDED) {
    unsigned short* zb = (unsigned short*)(ws + WS_ZB);
    unsigned short* ebuf = (unsigned short*)(ws + WS_EB);
    u64* tt2 = (u64*)(ws + WS_TT2);
    float* zsq4 = (float*)(ws + WS_ZSQ4);
    conv_kernel<<<2048, 256, 0, stream>>>(z, E, zb, ebuf, zsq4);
    zsqfin_kernel<<<64, 256, 0, stream>>>(zsq4, zsq);
    dim3 g(MTOT / 128, NCODES / 128);
    gemm_kernel<<<g, 256, 0, stream>>>(zb, ebuf, tt2);
    refine_kernel<<<MTOT / 4, 256, 0, stream>>>(z, E, zsq, enorm, tt2, packed);
  } else {
    hipMemsetAsync(packed, 0xFF, MTOT * 8, stream);
    zsq_kernel<<<64, 256, 0, stream>>>(z, zsq);
    dim3 g(MTOT / BM, NCODES / BN);
    dist_kernel<<<g, 256, 0, stream>>>(z, E, zsq, enorm, packed);
  }

  out_kernel<<<MTOT / 32, 256, 0, stream>>>(z, E, packed, out, loss_acc);
  idx_kernel<<<MTOT / 256, 256, 0, stream>>>(packed, out + OUT_ELEMS, counts);
  scalar_kernel<<<1, 256, 0, stream>>>(counts, loss_acc, out);
}

// Round 4
// 174.763 us; speedup vs baseline: 6.3912x; 1.2119x over previous
//
#include <hip/hip_runtime.h>
#include <stdint.h>

typedef unsigned long long u64;
typedef unsigned int u32;

#define CDIM 256
#define NCODES 8192
#define MTOT 16384
#define OUT_ELEMS 4194304   // 16*256*32*32
#define BETA 0.25f

// ws layout (bytes)
#define WS_PACKED 0u            // 16384*8 = 131072
#define WS_ENORM  131072u       // 32768
#define WS_ZSQ    163840u       // 65536
#define WS_COUNTS 229376u       // 32768
#define WS_LOSS   262144u       // 256 (only 4 used)
#define WS_ZSQ4   262400u       // 16384*4*4 = 262144
#define WS_ZB     524544u       // 16384*256*2 = 8388608
#define WS_EB     8913152u      // 8192*256*2 = 4194304
#define WS_TT2    13107456u     // 16384*64*8 = 8388608 (uint2 keys)
#define WS_NEEDED 21496064u

typedef short bf16x8 __attribute__((ext_vector_type(8)));
typedef float f32x4 __attribute__((ext_vector_type(4)));

#define GL2LDS16(g, l) __builtin_amdgcn_global_load_lds(            \
    (const __attribute__((address_space(1))) void*)(g),             \
    (__attribute__((address_space(3))) void*)(l), 16, 0, 0)

__device__ __forceinline__ unsigned short f2bf(float f) {
  u32 u = __float_as_uint(f);
  u32 r = (u + 0x7FFFu + ((u >> 16) & 1u)) >> 16;   // RNE
  return (unsigned short)r;
}
// monotone float->u32 (ascending) and inverse
__device__ __forceinline__ u32 encf(float f) {
  u32 u = __float_as_uint(f);
  return u ^ (u32)(((int)u >> 31) | 0x80000000);
}
__device__ __forceinline__ float decf(u32 u) {
  u32 v = u ^ ((((int)u) >= 0) ? 0xFFFFFFFFu : 0x80000000u);
  return __uint_as_float(v);
}

// ---------------- convert: z NCHW->NHWC bf16 (+zsq partials), E->bf16 ----------------
__global__ void conv_kernel(const float* __restrict__ z, const float* __restrict__ E,
                            unsigned short* __restrict__ zb, unsigned short* __restrict__ eb,
                            float* __restrict__ zsq4) {
  int blk = blockIdx.x;
  int t = threadIdx.x, w = t >> 6, lane = t & 63;
  if (blk < 1024) {
    __shared__ unsigned short tz[64][66];
    __shared__ float part[4][64];
    int b = blk >> 6, rem = blk & 63;
    int ct = rem >> 4, pt = rem & 15;
    int c0 = ct << 6, p0 = pt << 6;
    const float* zp = z + ((size_t)b << 18) + ((size_t)c0 << 10) + p0;
    float sq = 0.f;
    #pragma unroll
    for (int i = 0; i < 16; ++i) {
      int cl = w + (i << 2);
      float v = zp[((size_t)cl << 10) + lane];
      sq = fmaf(v, v, sq);
      tz[cl][lane] = f2bf(v);
    }
    part[w][lane] = sq;
    __syncthreads();
    if (w == 0) {
      float s = ((part[0][lane] + part[1][lane]) + part[2][lane]) + part[3][lane];
      zsq4[(((size_t)b << 10) + p0 + lane) * 4 + ct] = s;
    }
    #pragma unroll
    for (int j = 0; j < 16; ++j) {
      int pl = w + (j << 2);
      zb[(((size_t)b << 10) + p0 + pl) * 256 + c0 + lane] = tz[lane][pl];
    }
  } else {
    int e4 = blk - 1024;
    size_t base = ((size_t)e4 << 11) + ((size_t)t << 3);
    float4 v0 = *(const float4*)&E[base];
    float4 v1 = *(const float4*)&E[base + 4];
    ushort4 o0 = { f2bf(v0.x), f2bf(v0.y), f2bf(v0.z), f2bf(v0.w) };
    ushort4 o1 = { f2bf(v1.x), f2bf(v1.y), f2bf(v1.z), f2bf(v1.w) };
    *(ushort4*)&eb[base] = o0;
    *(ushort4*)&eb[base + 4] = o1;
  }
}

__global__ void zsqfin_kernel(const float* __restrict__ zsq4, float* __restrict__ zsq) {
  int m = blockIdx.x * 256 + threadIdx.x;
  float4 v = *(const float4*)&zsq4[(size_t)m * 4];
  zsq[m] = ((v.x + v.y) + v.z) + v.w;
}

// ---------------- enorm ----------------
__global__ void enorm_kernel(const float* __restrict__ E, float* __restrict__ enorm) {
  int wave = threadIdx.x >> 6;
  int lane = threadIdx.x & 63;
  int n = blockIdx.x * 4 + wave;
  float4 v = reinterpret_cast<const float4*>(E + (size_t)n * CDIM)[lane];
  float s = v.x * v.x + v.y * v.y + v.z * v.z + v.w * v.w;
  #pragma unroll
  for (int off = 32; off; off >>= 1) s += __shfl_down(s, off, 64);
  if (lane == 0) enorm[n] = s;
}

// ---------------- K1: bf16 MFMA GEMM (BM=256,BN=128,BK=64, XOR-swizzled LDS)
// + per-row per-128-tile top-2 (u32 keys: enc(acc) max-semantics, low7=col) ----------------
__global__ __launch_bounds__(256, 2) void gemm_kernel(
    const unsigned short* __restrict__ zb, const unsigned short* __restrict__ eb,
    uint2* __restrict__ tt2) {
  __shared__ unsigned short As[256 * 64];   // 32 KB, row = 8 granules of 16B
  __shared__ unsigned short Bs[128 * 64];   // 16 KB
  const int t = threadIdx.x;
  const int w = t >> 6, lane = t & 63;
  const int r16 = lane & 15, kg = lane >> 4;
  const int m0 = blockIdx.x << 8, n0 = blockIdx.y << 7;

  f32x4 acc[4][8];
  #pragma unroll
  for (int i = 0; i < 4; ++i)
    #pragma unroll
    for (int j = 0; j < 8; ++j) acc[i][j] = (f32x4)0.f;

  // staging: thread t stages granule g=i*256+t -> (row=g>>3, stored j'=g&7),
  // source granule j = j' ^ (row&7)  (inverse-swizzled global source)
  const int jsw = ((t & 7) ^ ((t >> 3) & 7)) << 3;   // shorts
  const unsigned short* zsrc = zb + (((size_t)m0 + (t >> 3)) << 8) + jsw;
  const unsigned short* esrc = eb + (((size_t)n0 + (t >> 3)) << 8) + jsw;

  // read-side lane constants (byte offsets); row&7 == r16&7 for all fragments
  const int jx0 = ((kg ^ (r16 & 7)) << 4);
  const int jx1 = (((4 + kg) ^ (r16 & 7)) << 4);
  const int arow = ((w << 6) + r16) << 7;   // (w*64+r16)*128 bytes
  const int brow = r16 << 7;

  for (int kt = 0; kt < 4; ++kt) {
    if (kt) __syncthreads();
    const int ko = kt << 6;   // shorts
    #pragma unroll
    for (int i = 0; i < 8; ++i)
      GL2LDS16(zsrc + (i << 13) + ko, (char*)As + (i << 12) + (t << 4));
    #pragma unroll
    for (int i = 0; i < 4; ++i)
      GL2LDS16(esrc + (i << 13) + ko, (char*)Bs + (i << 12) + (t << 4));
    __syncthreads();
    #pragma unroll
    for (int s = 0; s < 2; ++s) {
      const int jx = s ? jx1 : jx0;
      bf16x8 af[4], bq[8];
      #pragma unroll
      for (int mi = 0; mi < 4; ++mi)
        af[mi] = *(const bf16x8*)((const char*)As + arow + (mi << 11) + jx);
      #pragma unroll
      for (int ni = 0; ni < 8; ++ni)
        bq[ni] = *(const bf16x8*)((const char*)Bs + brow + (ni << 11) + jx);
      #pragma unroll
      for (int mi = 0; mi < 4; ++mi)
        #pragma unroll
        for (int ni = 0; ni < 8; ++ni)
          acc[mi][ni] = __builtin_amdgcn_mfma_f32_16x16x32_bf16(af[mi], bq[ni], acc[mi][ni], 0, 0, 0);
    }
  }

  // epilogue: keys = enc(acc) (max-sem: larger key = larger dot = smaller d),
  // low 7 bits = column within 128-tile. Branchless top-2, 16-lane merge.
  u32 idxc[8];
  #pragma unroll
  for (int ni = 0; ni < 8; ++ni) idxc[ni] = (u32)((ni << 4) | r16);
  #pragma unroll
  for (int mi = 0; mi < 4; ++mi) {
    #pragma unroll
    for (int reg = 0; reg < 4; ++reg) {
      u32 a1 = 0u, a2 = 0u;
      #pragma unroll
      for (int ni = 0; ni < 8; ++ni) {
        u32 u = __float_as_uint(acc[mi][ni][reg]);
        u32 e = u ^ (u32)(((int)u >> 31) | 0x80000000);
        u32 key = (e & 0xFFFFFF80u) | idxc[ni];
        u32 tmin = key < a1 ? key : a1;
        a1 = a1 > key ? a1 : key;
        a2 = a2 > tmin ? a2 : tmin;
      }
      #pragma unroll
      for (int off = 1; off < 16; off <<= 1) {
        u32 b1 = (u32)__shfl_xor((int)a1, off, 16);
        u32 b2 = (u32)__shfl_xor((int)a2, off, 16);
        u32 tmin = a1 < b1 ? a1 : b1;
        a1 = a1 > b1 ? a1 : b1;
        b2 = a2 > b2 ? a2 : b2;
        a2 = b2 > tmin ? b2 : tmin;
      }
      if (r16 == 0) {
        int mrow = m0 + (w << 6) + (mi << 4) + (kg << 2) + reg;
        tt2[(size_t)mrow * 64 + blockIdx.y] = make_uint2(a1, a2);
      }
    }
  }
}

// ---------------- K2: exact fp32 refinement of candidates ----------------
__global__ __launch_bounds__(256) void refine_kernel(
    const float* __restrict__ z, const float* __restrict__ E,
    const float* __restrict__ zsq, const float* __restrict__ enorm,
    const uint2* __restrict__ tt2, u64* __restrict__ packed) {
  const int t = threadIdx.x, w = t >> 6, lane = t & 63;
  const int m = (blockIdx.x << 2) + w;
  const int b = m >> 10, p = m & 1023;
  uint2 c = tt2[(size_t)m * 64 + lane];     // lane <-> 128-wide tile
  float f0 = decf(c.x), f1 = decf(c.y);
  float fm = fmaxf(f0, f1);
  #pragma unroll
  for (int off = 1; off < 64; off <<= 1) fm = fmaxf(fm, __shfl_xor(fm, off, 64));
  float thr = fm - 1e-4f;                   // margin on dot scale (as round 2)
  const float* zbp = z + ((size_t)b << 18) + p;
  float zr0 = zbp[(size_t)(lane * 4 + 0) << 10];
  float zr1 = zbp[(size_t)(lane * 4 + 1) << 10];
  float zr2 = zbp[(size_t)(lane * 4 + 2) << 10];
  float zr3 = zbp[(size_t)(lane * 4 + 3) << 10];
  float zsqm = zsq[m];
  u64 best = ~0ull;
  #pragma unroll
  for (int s = 0; s < 2; ++s) {
    u32 ck = s ? c.y : c.x;
    float fv = s ? f1 : f0;
    u64 mask = __ballot(fv >= thr);
    while (mask) {
      int src = __ffsll((unsigned long long)mask) - 1;
      mask &= mask - 1;
      u32 key = (u32)__shfl((int)ck, src, 64);
      int idx = (src << 7) | (int)(key & 127u);
      const float4 e4 = *(const float4*)&E[(size_t)idx * CDIM + lane * 4];
      float pa = zr0 * e4.x;
      pa = fmaf(zr1, e4.y, pa);
      pa = fmaf(zr2, e4.z, pa);
      pa = fmaf(zr3, e4.w, pa);
      #pragma unroll
      for (int off = 1; off < 64; off <<= 1) pa += __shfl_xor(pa, off, 64);
      float ttv = zsqm + enorm[idx];
      float d = ttv - 2.0f * pa;            // exact reference rounding profile
      u64 k2 = ((u64)__float_as_uint(d) << 32) | (u32)idx;
      if (k2 < best) best = k2;             // lowest-index tie-break
    }
  }
  if (lane == 0) packed[m] = best;
}

// ---------------- fallback exact fp32 path ----------------
__global__ void zsq_kernel(const float* __restrict__ z, float* __restrict__ zsq) {
  int blk = blockIdx.x;
  int j = threadIdx.x;
  int b = blk >> 2;
  int p = ((blk & 3) << 8) + j;
  const float* zp = z + (size_t)b * (CDIM * 1024) + p;
  float acc = 0.f;
  #pragma unroll 8
  for (int c = 0; c < CDIM; ++c) {
    float v = zp[(size_t)c * 1024];
    acc += v * v;
  }
  zsq[(blk << 8) + j] = acc;
}

#define BM 128
#define BN 128
#define BK 32
__global__ __launch_bounds__(256, 2) void dist_kernel(
    const float* __restrict__ z, const float* __restrict__ E,
    const float* __restrict__ zsq, const float* __restrict__ enorm,
    unsigned long long* __restrict__ packed) {
  __shared__ float zs[BK][BM];
  __shared__ float es[BK][BN];
  const int t = threadIdx.x;
  const int m0 = blockIdx.x * BM;
  const int n0 = blockIdx.y * BN;
  const int b = m0 >> 10;
  const int p0 = m0 & 1023;
  const int zc = t >> 5;
  const int zm = (t & 31) << 2;
  const float* zbase = z + (size_t)b * 262144 + p0 + zm;
  const int en = t & 127;
  const int ec = (t >> 7) << 4;
  const float* ebase = E + (size_t)(n0 + en) * CDIM + ec;
  float4 zr[4], er[4];
  #pragma unroll
  for (int r = 0; r < 4; ++r)
    zr[r] = *(const float4*)(zbase + (size_t)(r * 8 + zc) * 1024);
  #pragma unroll
  for (int i = 0; i < 4; ++i)
    er[i] = *(const float4*)(ebase + 4 * i);
  float acc[8][8];
  #pragma unroll
  for (int a = 0; a < 8; ++a)
    #pragma unroll
    for (int bb = 0; bb < 8; ++bb) acc[a][bb] = 0.f;
  const int tx = t & 15, ty = t >> 4;
  for (int kt = 0; kt < CDIM / BK; ++kt) {
    __syncthreads();
    #pragma unroll
    for (int r = 0; r < 4; ++r)
      *(float4*)&zs[r * 8 + zc][zm] = zr[r];
    #pragma unroll
    for (int i = 0; i < 4; ++i) {
      es[ec + 4 * i + 0][en] = er[i].x;
      es[ec + 4 * i + 1][en] = er[i].y;
      es[ec + 4 * i + 2][en] = er[i].z;
      es[ec + 4 * i + 3][en] = er[i].w;
    }
    __syncthreads();
    if (kt + 1 < CDIM / BK) {
      const int c0 = (kt + 1) * BK;
      #pragma unroll
      for (int r = 0; r < 4; ++r)
        zr[r] = *(const float4*)(zbase + (size_t)(c0 + r * 8 + zc) * 1024);
      #pragma unroll
      for (int i = 0; i < 4; ++i)
        er[i] = *(const float4*)(ebase + c0 + 4 * i);
    }
    #pragma unroll 8
    for (int kk = 0; kk < BK; ++kk) {
      float4 za = *(const float4*)&zs[kk][ty * 4];
      float4 zb4 = *(const float4*)&zs[kk][64 + ty * 4];
      float4 ea = *(const float4*)&es[kk][tx * 4];
      float4 eb4 = *(const float4*)&es[kk][64 + tx * 4];
      float zv[8] = {za.x, za.y, za.z, za.w, zb4.x, zb4.y, zb4.z, zb4.w};
      float ev[8] = {ea.x, ea.y, ea.z, ea.w, eb4.x, eb4.y, eb4.z, eb4.w};
      #pragma unroll
      for (int a = 0; a < 8; ++a)
        #pragma unroll
        for (int bb = 0; bb < 8; ++bb)
          acc[a][bb] += zv[a] * ev[bb];
    }
  }
  #pragma unroll
  for (int a = 0; a < 8; ++a) {
    int rloc = (a < 4) ? (ty * 4 + a) : (64 + ty * 4 + (a - 4));
    float zq = zsq[m0 + rloc];
    float bestd = 3.4e38f;
    int bestn = 0;
    #pragma unroll
    for (int bb = 0; bb < 8; ++bb) {
      int nloc = (bb < 4) ? (tx * 4 + bb) : (64 + tx * 4 + (bb - 4));
      int n = n0 + nloc;
      float ttv = zq + enorm[n];
      float d = ttv - 2.0f * acc[a][bb];
      if (d < bestd) { bestd = d; bestn = n; }
    }
    unsigned long long pk =
        ((unsigned long long)__float_as_uint(bestd) << 32) | (unsigned)bestn;
    #pragma unroll
    for (int off = 1; off < 16; off <<= 1) {
      unsigned long long other = __shfl_xor(pk, off, 16);
      if (other < pk) pk = other;
    }
    if (tx == 0) atomicMin(&packed[m0 + rloc], pk);
  }
}

// ---------------- gather z_q via LDS transpose, write out (ST), loss partial ----------------
__global__ __launch_bounds__(256) void out_kernel(
    const float* __restrict__ z, const float* __restrict__ E,
    const u64* __restrict__ packed,
    float* __restrict__ out, float* __restrict__ loss_acc) {
  __shared__ float es[32][257];
  const int t = threadIdx.x, w = t >> 6, lane = t & 63;
  const int m0 = blockIdx.x << 5;          // 512 blocks
  const int b = m0 >> 10, p0 = m0 & 1023;

  #pragma unroll
  for (int i = 0; i < 8; ++i) {
    int pl = (w << 3) + i;
    int idx = (int)(u32)(packed[m0 + pl] & 0xffffffffull);
    float4 v = *(const float4*)&E[((size_t)idx << 8) + (lane << 2)];
    es[pl][(lane << 2) + 0] = v.x;
    es[pl][(lane << 2) + 1] = v.y;
    es[pl][(lane << 2) + 2] = v.z;
    es[pl][(lane << 2) + 3] = v.w;
  }
  __syncthreads();

  const int pp = lane & 31, chi = lane >> 5;
  const size_t gbase = ((size_t)b << 18) + p0 + pp;
  float s = 0.f;
  #pragma unroll 8
  for (int i = 0; i < 32; ++i) {
    int c = (i << 3) + (w << 1) + chi;
    float zv = z[gbase + ((size_t)c << 10)];
    float e = es[pp][c];
    float diff = e - zv;
    out[gbase + ((size_t)c << 10)] = zv + diff;
    s = fmaf(diff, diff, s);
  }
  #pragma unroll
  for (int off = 32; off; off >>= 1) s += __shfl_down(s, off, 64);
  __shared__ float red[4];
  if (lane == 0) red[w] = s;
  __syncthreads();
  if (t == 0) atomicAdd(loss_acc, red[0] + red[1] + red[2] + red[3]);
}

__global__ void idx_kernel(const unsigned long long* __restrict__ packed,
                           float* __restrict__ out_idx, unsigned int* __restrict__ counts) {
  int m = blockIdx.x * 256 + threadIdx.x;
  int idx = (int)(unsigned)(packed[m] & 0xffffffffull);
  out_idx[m] = (float)idx;
  atomicAdd(&counts[idx], 1u);
}

__global__ void scalar_kernel(const unsigned int* __restrict__ counts,
                              const float* __restrict__ loss_acc,
                              float* __restrict__ out) {
  float s = 0.f;
  for (int i = threadIdx.x; i < NCODES; i += 256) {
    float pl = (float)counts[i] * (1.0f / 16384.0f);
    s += pl * logf(pl + 1e-10f);
  }
  #pragma unroll
  for (int off = 32; off; off >>= 1) s += __shfl_down(s, off, 64);
  __shared__ float red[4];
  int wv = threadIdx.x >> 6, lane = threadIdx.x & 63;
  if (lane == 0) red[wv] = s;
  __syncthreads();
  if (threadIdx.x == 0) {
    float tot = red[0] + red[1] + red[2] + red[3];
    out[OUT_ELEMS + MTOT] = (1.0f + BETA) * loss_acc[0] * (1.0f / (float)OUT_ELEMS);
    out[OUT_ELEMS + MTOT + 1] = expf(-tot);
  }
}

extern "C" void kernel_launch(void* const* d_in, const int* in_sizes, int n_in,
                              void* d_out, int out_size, void* d_ws, size_t ws_size,
                              hipStream_t stream) {
  const float* z = (const float*)d_in[0];
  const float* E = (const float*)d_in[1];
  float* out = (float*)d_out;
  char* ws = (char*)d_ws;
  u64* packed = (u64*)(ws + WS_PACKED);
  float* enorm = (float*)(ws + WS_ENORM);
  float* zsq = (float*)(ws + WS_ZSQ);
  u32* counts = (u32*)(ws + WS_COUNTS);
  float* loss_acc = (float*)(ws + WS_LOSS);

  hipMemsetAsync(counts, 0, 32768 + 256, stream);  // counts + loss_acc
  enorm_kernel<<<NCODES / 4, 256, 0, stream>>>(E, enorm);

  if (ws_size >= WS_NEEDED) {
    unsigned short* zb = (unsigned short*)(ws + WS_ZB);
    unsigned short* ebuf = (unsigned short*)(ws + WS_EB);
    uint2* tt2 = (uint2*)(ws + WS_TT2);
    float* zsq4 = (float*)(ws + WS_ZSQ4);
    conv_kernel<<<2048, 256, 0, stream>>>(z, E, zb, ebuf, zsq4);
    zsqfin_kernel<<<64, 256, 0, stream>>>(zsq4, zsq);
    dim3 g(MTOT / 256, NCODES / 128);
    gemm_kernel<<<g, 256, 0, stream>>>(zb, ebuf, tt2);
    refine_kernel<<<MTOT / 4, 256, 0, stream>>>(z, E, zsq, enorm, tt2, packed);
  } else {
    hipMemsetAsync(packed, 0xFF, MTOT * 8, stream);
    zsq_kernel<<<64, 256, 0, stream>>>(z, zsq);
    dim3 g(MTOT / BM, NCODES / BN);
    dist_kernel<<<g, 256, 0, stream>>>(z, E, zsq, enorm, packed);
  }

  out_kernel<<<MTOT / 32, 256, 0, stream>>>(z, E, packed, out, loss_acc);
  idx_kernel<<<MTOT / 256, 256, 0, stream>>>(packed, out + OUT_ELEMS, counts);
  scalar_kernel<<<1, 256, 0, stream>>>(counts, loss_acc, out);
}

// Round 5
// 159.709 us; speedup vs baseline: 6.9936x; 1.0943x over previous
//
#include <hip/hip_runtime.h>
#include <stdint.h>

typedef unsigned long long u64;
typedef unsigned int u32;

#define CDIM 256
#define NCODES 8192
#define MTOT 16384
#define OUT_ELEMS 4194304   // 16*256*32*32
#define BETA 0.25f

// ws layout (bytes)
#define WS_PACKED 0u            // 16384*8 = 131072
#define WS_ENORM  131072u       // 32768
#define WS_ZSQ    163840u       // 65536
#define WS_COUNTS 229376u       // 32768
#define WS_LOSS   262144u       // 256 (only 4 used)
#define WS_ZSQ4   262400u       // 16384*4*4 = 262144
#define WS_ZB     524544u       // 16384*256*2 = 8388608
#define WS_EB     8913152u      // 8192*256*2 = 4194304
#define WS_TT2    13107456u     // 64*16384*8 = 8388608 (uint2 keys, [tile][m])
#define WS_NEEDED 21496064u

typedef short bf16x8 __attribute__((ext_vector_type(8)));
typedef float f32x4 __attribute__((ext_vector_type(4)));

#define GL2LDS16(g, l) __builtin_amdgcn_global_load_lds(            \
    (const __attribute__((address_space(1))) void*)(g),             \
    (__attribute__((address_space(3))) void*)(l), 16, 0, 0)

__device__ __forceinline__ unsigned short f2bf(float f) {
  u32 u = __float_as_uint(f);
  u32 r = (u + 0x7FFFu + ((u >> 16) & 1u)) >> 16;   // RNE
  return (unsigned short)r;
}

// ---------------- convert: z NCHW->NHWC bf16 (+zsq partials), E->bf16 ----------------
__global__ void conv_kernel(const float* __restrict__ z, const float* __restrict__ E,
                            unsigned short* __restrict__ zb, unsigned short* __restrict__ eb,
                            float* __restrict__ zsq4) {
  int blk = blockIdx.x;
  int t = threadIdx.x, w = t >> 6, lane = t & 63;
  if (blk < 1024) {
    __shared__ unsigned short tz[64][66];
    __shared__ float part[4][64];
    int b = blk >> 6, rem = blk & 63;
    int ct = rem >> 4, pt = rem & 15;
    int c0 = ct << 6, p0 = pt << 6;
    const float* zp = z + ((size_t)b << 18) + ((size_t)c0 << 10) + p0;
    float sq = 0.f;
    #pragma unroll
    for (int i = 0; i < 16; ++i) {
      int cl = w + (i << 2);
      float v = zp[((size_t)cl << 10) + lane];
      sq = fmaf(v, v, sq);
      tz[cl][lane] = f2bf(v);
    }
    part[w][lane] = sq;
    __syncthreads();
    if (w == 0) {
      float s = ((part[0][lane] + part[1][lane]) + part[2][lane]) + part[3][lane];
      zsq4[(((size_t)b << 10) + p0 + lane) * 4 + ct] = s;
    }
    #pragma unroll
    for (int j = 0; j < 16; ++j) {
      int pl = w + (j << 2);
      zb[(((size_t)b << 10) + p0 + pl) * 256 + c0 + lane] = tz[lane][pl];
    }
  } else {
    int e4 = blk - 1024;
    size_t base = ((size_t)e4 << 11) + ((size_t)t << 3);
    float4 v0 = *(const float4*)&E[base];
    float4 v1 = *(const float4*)&E[base + 4];
    ushort4 o0 = { f2bf(v0.x), f2bf(v0.y), f2bf(v0.z), f2bf(v0.w) };
    ushort4 o1 = { f2bf(v1.x), f2bf(v1.y), f2bf(v1.z), f2bf(v1.w) };
    *(ushort4*)&eb[base] = o0;
    *(ushort4*)&eb[base + 4] = o1;
  }
}

__global__ void zsqfin_kernel(const float* __restrict__ zsq4, float* __restrict__ zsq) {
  int m = blockIdx.x * 256 + threadIdx.x;
  float4 v = *(const float4*)&zsq4[(size_t)m * 4];
  zsq[m] = ((v.x + v.y) + v.z) + v.w;
}

// ---------------- enorm ----------------
__global__ void enorm_kernel(const float* __restrict__ E, float* __restrict__ enorm) {
  int wave = threadIdx.x >> 6;
  int lane = threadIdx.x & 63;
  int n = blockIdx.x * 4 + wave;
  float4 v = reinterpret_cast<const float4*>(E + (size_t)n * CDIM)[lane];
  float s = v.x * v.x + v.y * v.y + v.z * v.z + v.w * v.w;
  #pragma unroll
  for (int off = 32; off; off >>= 1) s += __shfl_down(s, off, 64);
  if (lane == 0) enorm[n] = s;
}

// ---------------- K1: bf16 MFMA GEMM (BM=256,BN=128,BK=64, XOR-swizzled LDS)
// Swapped operands: mfma(code_frag, z_frag) -> each lane owns full rows.
// Keys: as_float((as_uint(dot+2)& ~127)|col), fmed3-based in-lane top-2. ----------------
__global__ __launch_bounds__(256, 2) void gemm_kernel(
    const unsigned short* __restrict__ zb, const unsigned short* __restrict__ eb,
    uint2* __restrict__ tt2) {
  __shared__ unsigned short As[256 * 64];   // 32 KB, row = 8 granules of 16B
  __shared__ unsigned short Bs[128 * 64];   // 16 KB
  const int t = threadIdx.x;
  const int w = t >> 6, lane = t & 63;
  const int r16 = lane & 15, kg = lane >> 4;
  const int m0 = blockIdx.x << 8, n0 = blockIdx.y << 7;

  f32x4 acc[4][8];
  #pragma unroll
  for (int i = 0; i < 4; ++i)
    #pragma unroll
    for (int j = 0; j < 8; ++j) acc[i][j] = (f32x4)0.f;

  // staging: thread t stages granule g=i*256+t -> (row=g>>3, stored j'=g&7),
  // source granule j = j' ^ (row&7)  (inverse-swizzled global source)
  const int jsw = ((t & 7) ^ ((t >> 3) & 7)) << 3;   // shorts
  const unsigned short* zsrc = zb + (((size_t)m0 + (t >> 3)) << 8) + jsw;
  const unsigned short* esrc = eb + (((size_t)n0 + (t >> 3)) << 8) + jsw;

  // read-side lane constants (byte offsets); row&7 == r16&7 for all fragments
  const int jx0 = ((kg ^ (r16 & 7)) << 4);
  const int jx1 = (((4 + kg) ^ (r16 & 7)) << 4);
  const int arow = ((w << 6) + r16) << 7;   // (w*64+r16)*128 bytes
  const int brow = r16 << 7;

  for (int kt = 0; kt < 4; ++kt) {
    if (kt) __syncthreads();
    const int ko = kt << 6;   // shorts
    #pragma unroll
    for (int i = 0; i < 8; ++i)
      GL2LDS16(zsrc + (i << 13) + ko, (char*)As + (i << 12) + (t << 4));
    #pragma unroll
    for (int i = 0; i < 4; ++i)
      GL2LDS16(esrc + (i << 13) + ko, (char*)Bs + (i << 12) + (t << 4));
    __syncthreads();
    #pragma unroll
    for (int s = 0; s < 2; ++s) {
      const int jx = s ? jx1 : jx0;
      bf16x8 af[4], bq[8];
      #pragma unroll
      for (int mi = 0; mi < 4; ++mi)
        af[mi] = *(const bf16x8*)((const char*)As + arow + (mi << 11) + jx);
      #pragma unroll
      for (int ni = 0; ni < 8; ++ni)
        bq[ni] = *(const bf16x8*)((const char*)Bs + brow + (ni << 11) + jx);
      #pragma unroll
      for (int mi = 0; mi < 4; ++mi)
        #pragma unroll
        for (int ni = 0; ni < 8; ++ni)
          acc[mi][ni] = __builtin_amdgcn_mfma_f32_16x16x32_bf16(bq[ni], af[mi], acc[mi][ni], 0, 0, 0);
    }
  }

  // epilogue: lane's z-row (per mi) = w*64+mi*16+r16; code col = ni*16+kg*4+reg.
  // In-lane top-2 over 32 codes (fmed3/fmax), then 2-step cross-kg merge.
  const u32 kgr = (u32)(kg << 2);
  #pragma unroll
  for (int mi = 0; mi < 4; ++mi) {
    float a1 = 0.f, a2 = 0.f;
    #pragma unroll
    for (int ni = 0; ni < 8; ++ni) {
      #pragma unroll
      for (int reg = 0; reg < 4; ++reg) {
        u32 e = __float_as_uint(acc[mi][ni][reg] + 2.0f);
        float k = __uint_as_float((e & 0xFFFFFF80u) | ((u32)(ni << 4) | kgr | (u32)reg));
        float na2 = __builtin_amdgcn_fmed3f(a1, a2, k);
        a1 = fmaxf(a1, k);
        a2 = na2;
      }
    }
    #pragma unroll
    for (int off = 16; off < 64; off <<= 1) {
      float b1 = __shfl_xor(a1, off, 64);
      float b2 = __shfl_xor(a2, off, 64);
      a2 = fmaxf(fminf(a1, b1), fmaxf(a2, b2));
      a1 = fmaxf(a1, b1);
    }
    if (kg == 0) {
      int row = m0 + (w << 6) + (mi << 4) + r16;
      tt2[((size_t)blockIdx.y << 14) + row] =
          make_uint2(__float_as_uint(a1), __float_as_uint(a2));
    }
  }
}

// ---------------- K2: exact fp32 refinement of candidates ----------------
__global__ __launch_bounds__(256) void refine_kernel(
    const float* __restrict__ z, const float* __restrict__ E,
    const float* __restrict__ zsq, const float* __restrict__ enorm,
    const uint2* __restrict__ tt2, u64* __restrict__ packed) {
  const int t = threadIdx.x, w = t >> 6, lane = t & 63;
  const int m = (blockIdx.x << 2) + w;
  const int b = m >> 10, p = m & 1023;
  uint2 c = tt2[((size_t)lane << 14) + m];  // lane <-> 128-wide tile
  float f0 = __uint_as_float(c.x), f1 = __uint_as_float(c.y);  // f0 >= f1
  float fm = f0;
  #pragma unroll
  for (int off = 1; off < 64; off <<= 1) fm = fmaxf(fm, __shfl_xor(fm, off, 64));
  float thr = fm - 1.5e-4f;                 // margin on (dot+2) scale
  const float* zbp = z + ((size_t)b << 18) + p;
  float zr0 = zbp[(size_t)(lane * 4 + 0) << 10];
  float zr1 = zbp[(size_t)(lane * 4 + 1) << 10];
  float zr2 = zbp[(size_t)(lane * 4 + 2) << 10];
  float zr3 = zbp[(size_t)(lane * 4 + 3) << 10];
  float zsqm = zsq[m];
  u64 best = ~0ull;
  #pragma unroll
  for (int s = 0; s < 2; ++s) {
    u32 ck = s ? c.y : c.x;
    float fv = s ? f1 : f0;
    u64 mask = __ballot(fv >= thr);
    while (mask) {
      int src = __ffsll((unsigned long long)mask) - 1;
      mask &= mask - 1;
      u32 key = (u32)__shfl((int)ck, src, 64);
      int idx = (src << 7) | (int)(key & 127u);
      const float4 e4 = *(const float4*)&E[(size_t)idx * CDIM + lane * 4];
      float pa = zr0 * e4.x;
      pa = fmaf(zr1, e4.y, pa);
      pa = fmaf(zr2, e4.z, pa);
      pa = fmaf(zr3, e4.w, pa);
      #pragma unroll
      for (int off = 1; off < 64; off <<= 1) pa += __shfl_xor(pa, off, 64);
      float ttv = zsqm + enorm[idx];
      float d = ttv - 2.0f * pa;            // exact reference rounding profile
      u64 k2 = ((u64)__float_as_uint(d) << 32) | (u32)idx;
      if (k2 < best) best = k2;             // lowest-index tie-break
    }
  }
  if (lane == 0) packed[m] = best;
}

// ---------------- fallback exact fp32 path ----------------
__global__ void zsq_kernel(const float* __restrict__ z, float* __restrict__ zsq) {
  int blk = blockIdx.x;
  int j = threadIdx.x;
  int b = blk >> 2;
  int p = ((blk & 3) << 8) + j;
  const float* zp = z + (size_t)b * (CDIM * 1024) + p;
  float acc = 0.f;
  #pragma unroll 8
  for (int c = 0; c < CDIM; ++c) {
    float v = zp[(size_t)c * 1024];
    acc += v * v;
  }
  zsq[(blk << 8) + j] = acc;
}

#define BM 128
#define BN 128
#define BK 32
__global__ __launch_bounds__(256, 2) void dist_kernel(
    const float* __restrict__ z, const float* __restrict__ E,
    const float* __restrict__ zsq, const float* __restrict__ enorm,
    unsigned long long* __restrict__ packed) {
  __shared__ float zs[BK][BM];
  __shared__ float es[BK][BN];
  const int t = threadIdx.x;
  const int m0 = blockIdx.x * BM;
  const int n0 = blockIdx.y * BN;
  const int b = m0 >> 10;
  const int p0 = m0 & 1023;
  const int zc = t >> 5;
  const int zm = (t & 31) << 2;
  const float* zbase = z + (size_t)b * 262144 + p0 + zm;
  const int en = t & 127;
  const int ec = (t >> 7) << 4;
  const float* ebase = E + (size_t)(n0 + en) * CDIM + ec;
  float4 zr[4], er[4];
  #pragma unroll
  for (int r = 0; r < 4; ++r)
    zr[r] = *(const float4*)(zbase + (size_t)(r * 8 + zc) * 1024);
  #pragma unroll
  for (int i = 0; i < 4; ++i)
    er[i] = *(const float4*)(ebase + 4 * i);
  float acc[8][8];
  #pragma unroll
  for (int a = 0; a < 8; ++a)
    #pragma unroll
    for (int bb = 0; bb < 8; ++bb) acc[a][bb] = 0.f;
  const int tx = t & 15, ty = t >> 4;
  for (int kt = 0; kt < CDIM / BK; ++kt) {
    __syncthreads();
    #pragma unroll
    for (int r = 0; r < 4; ++r)
      *(float4*)&zs[r * 8 + zc][zm] = zr[r];
    #pragma unroll
    for (int i = 0; i < 4; ++i) {
      es[ec + 4 * i + 0][en] = er[i].x;
      es[ec + 4 * i + 1][en] = er[i].y;
      es[ec + 4 * i + 2][en] = er[i].z;
      es[ec + 4 * i + 3][en] = er[i].w;
    }
    __syncthreads();
    if (kt + 1 < CDIM / BK) {
      const int c0 = (kt + 1) * BK;
      #pragma unroll
      for (int r = 0; r < 4; ++r)
        zr[r] = *(const float4*)(zbase + (size_t)(c0 + r * 8 + zc) * 1024);
      #pragma unroll
      for (int i = 0; i < 4; ++i)
        er[i] = *(const float4*)(ebase + c0 + 4 * i);
    }
    #pragma unroll 8
    for (int kk = 0; kk < BK; ++kk) {
      float4 za = *(const float4*)&zs[kk][ty * 4];
      float4 zb4 = *(const float4*)&zs[kk][64 + ty * 4];
      float4 ea = *(const float4*)&es[kk][tx * 4];
      float4 eb4 = *(const float4*)&es[kk][64 + tx * 4];
      float zv[8] = {za.x, za.y, za.z, za.w, zb4.x, zb4.y, zb4.z, zb4.w};
      float ev[8] = {ea.x, ea.y, ea.z, ea.w, eb4.x, eb4.y, eb4.z, eb4.w};
      #pragma unroll
      for (int a = 0; a < 8; ++a)
        #pragma unroll
        for (int bb = 0; bb < 8; ++bb)
          acc[a][bb] += zv[a] * ev[bb];
    }
  }
  #pragma unroll
  for (int a = 0; a < 8; ++a) {
    int rloc = (a < 4) ? (ty * 4 + a) : (64 + ty * 4 + (a - 4));
    float zq = zsq[m0 + rloc];
    float bestd = 3.4e38f;
    int bestn = 0;
    #pragma unroll
    for (int bb = 0; bb < 8; ++bb) {
      int nloc = (bb < 4) ? (tx * 4 + bb) : (64 + tx * 4 + (bb - 4));
      int n = n0 + nloc;
      float ttv = zq + enorm[n];
      float d = ttv - 2.0f * acc[a][bb];
      if (d < bestd) { bestd = d; bestn = n; }
    }
    unsigned long long pk =
        ((unsigned long long)__float_as_uint(bestd) << 32) | (unsigned)bestn;
    #pragma unroll
    for (int off = 1; off < 16; off <<= 1) {
      unsigned long long other = __shfl_xor(pk, off, 16);
      if (other < pk) pk = other;
    }
    if (tx == 0) atomicMin(&packed[m0 + rloc], pk);
  }
}

// ---------------- gather z_q via LDS transpose, write out (ST), loss partial ----------------
__global__ __launch_bounds__(256) void out_kernel(
    const float* __restrict__ z, const float* __restrict__ E,
    const u64* __restrict__ packed,
    float* __restrict__ out, float* __restrict__ loss_acc) {
  __shared__ float es[32][257];
  const int t = threadIdx.x, w = t >> 6, lane = t & 63;
  const int m0 = blockIdx.x << 5;          // 512 blocks
  const int b = m0 >> 10, p0 = m0 & 1023;

  #pragma unroll
  for (int i = 0; i < 8; ++i) {
    int pl = (w << 3) + i;
    int idx = (int)(u32)(packed[m0 + pl] & 0xffffffffull);
    float4 v = *(const float4*)&E[((size_t)idx << 8) + (lane << 2)];
    es[pl][(lane << 2) + 0] = v.x;
    es[pl][(lane << 2) + 1] = v.y;
    es[pl][(lane << 2) + 2] = v.z;
    es[pl][(lane << 2) + 3] = v.w;
  }
  __syncthreads();

  const int pp = lane & 31, chi = lane >> 5;
  const size_t gbase = ((size_t)b << 18) + p0 + pp;
  float s = 0.f;
  #pragma unroll 8
  for (int i = 0; i < 32; ++i) {
    int c = (i << 3) + (w << 1) + chi;
    float zv = z[gbase + ((size_t)c << 10)];
    float e = es[pp][c];
    float diff = e - zv;
    out[gbase + ((size_t)c << 10)] = zv + diff;
    s = fmaf(diff, diff, s);
  }
  #pragma unroll
  for (int off = 32; off; off >>= 1) s += __shfl_down(s, off, 64);
  __shared__ float red[4];
  if (lane == 0) red[w] = s;
  __syncthreads();
  if (t == 0) atomicAdd(loss_acc, red[0] + red[1] + red[2] + red[3]);
}

__global__ void idx_kernel(const unsigned long long* __restrict__ packed,
                           float* __restrict__ out_idx, unsigned int* __restrict__ counts) {
  int m = blockIdx.x * 256 + threadIdx.x;
  int idx = (int)(unsigned)(packed[m] & 0xffffffffull);
  out_idx[m] = (float)idx;
  atomicAdd(&counts[idx], 1u);
}

__global__ void scalar_kernel(const unsigned int* __restrict__ counts,
                              const float* __restrict__ loss_acc,
                              float* __restrict__ out) {
  float s = 0.f;
  for (int i = threadIdx.x; i < NCODES; i += 256) {
    float pl = (float)counts[i] * (1.0f / 16384.0f);
    s += pl * logf(pl + 1e-10f);
  }
  #pragma unroll
  for (int off = 32; off; off >>= 1) s += __shfl_down(s, off, 64);
  __shared__ float red[4];
  int wv = threadIdx.x >> 6, lane = threadIdx.x & 63;
  if (lane == 0) red[wv] = s;
  __syncthreads();
  if (threadIdx.x == 0) {
    float tot = red[0] + red[1] + red[2] + red[3];
    out[OUT_ELEMS + MTOT] = (1.0f + BETA) * loss_acc[0] * (1.0f / (float)OUT_ELEMS);
    out[OUT_ELEMS + MTOT + 1] = expf(-tot);
  }
}

extern "C" void kernel_launch(void* const* d_in, const int* in_sizes, int n_in,
                              void* d_out, int out_size, void* d_ws, size_t ws_size,
                              hipStream_t stream) {
  const float* z = (const float*)d_in[0];
  const float* E = (const float*)d_in[1];
  float* out = (float*)d_out;
  char* ws = (char*)d_ws;
  u64* packed = (u64*)(ws + WS_PACKED);
  float* enorm = (float*)(ws + WS_ENORM);
  float* zsq = (float*)(ws + WS_ZSQ);
  u32* counts = (u32*)(ws + WS_COUNTS);
  float* loss_acc = (float*)(ws + WS_LOSS);

  hipMemsetAsync(counts, 0, 32768 + 256, stream);  // counts + loss_acc
  enorm_kernel<<<NCODES / 4, 256, 0, stream>>>(E, enorm);

  if (ws_size >= WS_NEEDED) {
    unsigned short* zb = (unsigned short*)(ws + WS_ZB);
    unsigned short* ebuf = (unsigned short*)(ws + WS_EB);
    uint2* tt2 = (uint2*)(ws + WS_TT2);
    float* zsq4 = (float*)(ws + WS_ZSQ4);
    conv_kernel<<<2048, 256, 0, stream>>>(z, E, zb, ebuf, zsq4);
    zsqfin_kernel<<<64, 256, 0, stream>>>(zsq4, zsq);
    dim3 g(MTOT / 256, NCODES / 128);
    gemm_kernel<<<g, 256, 0, stream>>>(zb, ebuf, tt2);
    refine_kernel<<<MTOT / 4, 256, 0, stream>>>(z, E, zsq, enorm, tt2, packed);
  } else {
    hipMemsetAsync(packed, 0xFF, MTOT * 8, stream);
    zsq_kernel<<<64, 256, 0, stream>>>(z, zsq);
    dim3 g(MTOT / BM, NCODES / BN);
    dist_kernel<<<g, 256, 0, stream>>>(z, E, zsq, enorm, packed);
  }

  out_kernel<<<MTOT / 32, 256, 0, stream>>>(z, E, packed, out, loss_acc);
  idx_kernel<<<MTOT / 256, 256, 0, stream>>>(packed, out + OUT_ELEMS, counts);
  scalar_kernel<<<1, 256, 0, stream>>>(counts, loss_acc, out);
}

// Round 6
// 135.934 us; speedup vs baseline: 8.2168x; 1.1749x over previous
//
#include <hip/hip_runtime.h>
#include <stdint.h>

typedef unsigned long long u64;
typedef unsigned int u32;

#define CDIM 256
#define NCODES 8192
#define MTOT 16384
#define OUT_ELEMS 4194304   // 16*256*32*32
#define BETA 0.25f

// ws layout (bytes)
#define WS_PACKED 0u            // 16384*8 = 131072
#define WS_ENORM  131072u       // 32768
#define WS_ZSQ    163840u       // 65536
#define WS_COUNTS 229376u       // 32768
#define WS_LOSS   262144u       // 256 (only 4 used)
#define WS_ZB     524544u       // 16384*256*2 = 8388608
#define WS_EB     8913152u      // 8192*256*2 = 4194304
#define WS_TT2    13107456u     // 64*16384*8 = 8388608 (uint2 keys, [tile][m])
#define WS_NEEDED 21496064u

typedef short bf16x8 __attribute__((ext_vector_type(8)));
typedef float f32x4 __attribute__((ext_vector_type(4)));
typedef float f32x16 __attribute__((ext_vector_type(16)));

#define GL2LDS16(g, l) __builtin_amdgcn_global_load_lds(            \
    (const __attribute__((address_space(1))) void*)(g),             \
    (__attribute__((address_space(3))) void*)(l), 16, 0, 0)

__device__ __forceinline__ unsigned short f2bf(float f) {
  u32 u = __float_as_uint(f);
  u32 r = (u + 0x7FFFu + ((u >> 16) & 1u)) >> 16;   // RNE
  return (unsigned short)r;
}

// ---------------- fused convert: z NCHW->NHWC bf16 + zsq;  E->bf16 + enorm ----------------
__global__ void conv_kernel(const float* __restrict__ z, const float* __restrict__ E,
                            unsigned short* __restrict__ zb, unsigned short* __restrict__ eb,
                            float* __restrict__ zsq, float* __restrict__ enorm) {
  int blk = blockIdx.x;
  int t = threadIdx.x, w = t >> 6, lane = t & 63;
  if (blk < 256) {
    __shared__ unsigned short tz[64][66];
    __shared__ float part[4][4][64];
    int b = blk >> 4, p0 = (blk & 15) << 6;
    const float* zp = z + ((size_t)b << 18) + p0;
    #pragma unroll
    for (int ct = 0; ct < 4; ++ct) {
      int c0 = ct << 6;
      if (ct) __syncthreads();           // protect tz reuse
      float s = 0.f;
      #pragma unroll
      for (int i = 0; i < 16; ++i) {
        int cl = w + (i << 2);
        float v = zp[((size_t)(c0 + cl) << 10) + lane];
        s = fmaf(v, v, s);
        tz[cl][lane] = f2bf(v);
      }
      part[ct][w][lane] = s;
      __syncthreads();
      #pragma unroll
      for (int j = 0; j < 16; ++j) {
        int pl = w + (j << 2);
        zb[(((size_t)b << 10) + p0 + pl) * 256 + c0 + lane] = tz[lane][pl];
      }
    }
    // same summation tree as prior rounds: quarters then ((q0+q1)+q2)+q3
    if (w == 0) {
      float q0 = ((part[0][0][lane] + part[0][1][lane]) + part[0][2][lane]) + part[0][3][lane];
      float q1 = ((part[1][0][lane] + part[1][1][lane]) + part[1][2][lane]) + part[1][3][lane];
      float q2 = ((part[2][0][lane] + part[2][1][lane]) + part[2][2][lane]) + part[2][3][lane];
      float q3 = ((part[3][0][lane] + part[3][1][lane]) + part[3][2][lane]) + part[3][3][lane];
      zsq[(b << 10) + p0 + lane] = ((q0 + q1) + q2) + q3;
    }
  } else {
    int e4 = blk - 256;                  // 1024 blocks, 8 E-rows each
    size_t base = ((size_t)e4 << 11) + ((size_t)t << 3);
    float4 v0 = *(const float4*)&E[base];
    float4 v1 = *(const float4*)&E[base + 4];
    ushort4 o0 = { f2bf(v0.x), f2bf(v0.y), f2bf(v0.z), f2bf(v0.w) };
    ushort4 o1 = { f2bf(v1.x), f2bf(v1.y), f2bf(v1.z), f2bf(v1.w) };
    *(ushort4*)&eb[base] = o0;
    *(ushort4*)&eb[base + 4] = o1;
    // enorm (order-insensitive: always rounds away against zsq)
    float s = v0.x * v0.x + v0.y * v0.y + v0.z * v0.z + v0.w * v0.w
            + v1.x * v1.x + v1.y * v1.y + v1.z * v1.z + v1.w * v1.w;
    #pragma unroll
    for (int off = 16; off; off >>= 1) s += __shfl_xor(s, off, 32);
    if ((t & 31) == 0) enorm[(e4 << 3) + (t >> 5)] = s;
  }
}

// ---------------- K1: bf16 MFMA GEMM (BM=256,BN=128,BK=64, XOR-swizzled LDS, 32x32x16)
// Swapped operands: mfma(code_frag, z_frag) -> lane owns whole z-rows.
// Keys: as_float((as_uint(dot+2) & ~127) | col), fmed3 in-lane top-2, 1-step merge. ----------
__global__ __launch_bounds__(256, 2) void gemm_kernel(
    const unsigned short* __restrict__ zb, const unsigned short* __restrict__ eb,
    uint2* __restrict__ tt2) {
  __shared__ unsigned short As[256 * 64];   // 32 KB, row = 8 granules of 16B
  __shared__ unsigned short Bs[128 * 64];   // 16 KB
  const int t = threadIdx.x;
  const int w = t >> 6, lane = t & 63;
  const int r32 = lane & 31, hi = lane >> 5, r7 = r32 & 7;
  const int m0 = blockIdx.x << 8, n0 = blockIdx.y << 7;

  f32x16 acc[2][4];
  #pragma unroll
  for (int i = 0; i < 2; ++i)
    #pragma unroll
    for (int j = 0; j < 4; ++j) acc[i][j] = (f32x16)0.f;

  // staging: thread t stages granule g=i*256+t -> (row=g>>3, slot j'=g&7),
  // source granule j = j' ^ (row&7)  (inverse-swizzled global source)
  const int jsw = ((t & 7) ^ ((t >> 3) & 7)) << 3;   // shorts
  const unsigned short* zsrc = zb + (((size_t)m0 + (t >> 3)) << 8) + jsw;
  const unsigned short* esrc = eb + (((size_t)n0 + (t >> 3)) << 8) + jsw;

  const int abase = ((w << 6) + r32) << 7;  // bytes: row (w*64 + r32) * 128
  const int bbase = r32 << 7;

  for (int kt = 0; kt < 4; ++kt) {
    if (kt) __syncthreads();
    const int ko = kt << 6;   // shorts
    #pragma unroll
    for (int i = 0; i < 8; ++i)
      GL2LDS16(zsrc + (i << 13) + ko, (char*)As + (i << 12) + (t << 4));
    #pragma unroll
    for (int i = 0; i < 4; ++i)
      GL2LDS16(esrc + (i << 13) + ko, (char*)Bs + (i << 12) + (t << 4));
    __syncthreads();
    #pragma unroll
    for (int ki = 0; ki < 4; ++ki) {
      const int jx = (((ki << 1) + hi) ^ r7) << 4;   // granule swizzle (bytes)
      bf16x8 af[2], bq[4];
      #pragma unroll
      for (int a = 0; a < 2; ++a)
        af[a] = *(const bf16x8*)((const char*)As + abase + (a << 12) + jx);
      #pragma unroll
      for (int ni = 0; ni < 4; ++ni)
        bq[ni] = *(const bf16x8*)((const char*)Bs + bbase + (ni << 12) + jx);
      #pragma unroll
      for (int a = 0; a < 2; ++a)
        #pragma unroll
        for (int ni = 0; ni < 4; ++ni)
          acc[a][ni] = __builtin_amdgcn_mfma_f32_32x32x16_bf16(bq[ni], af[a], acc[a][ni], 0, 0, 0);
    }
  }

  // epilogue: lane's z-row (per a) = w*64 + a*32 + r32;
  // code within 128-tile = ni*32 + (reg&3) + 8*(reg>>2) + 4*hi
  const u32 hib = (u32)(hi << 2);
  #pragma unroll
  for (int a = 0; a < 2; ++a) {
    float a1 = 0.f, a2 = 0.f;
    #pragma unroll
    for (int ni = 0; ni < 4; ++ni) {
      #pragma unroll
      for (int reg = 0; reg < 16; ++reg) {
        u32 code = ((u32)(ni << 5) | ((u32)(reg >> 2) << 3) | (u32)(reg & 3)) | hib;
        u32 e = __float_as_uint(acc[a][ni][reg] + 2.0f);
        float k = __uint_as_float((e & 0xFFFFFF80u) | code);
        float na2 = __builtin_amdgcn_fmed3f(a1, a2, k);
        a1 = fmaxf(a1, k);
        a2 = na2;
      }
    }
    float b1 = __shfl_xor(a1, 32, 64);
    float b2 = __shfl_xor(a2, 32, 64);
    a2 = fmaxf(fminf(a1, b1), fmaxf(a2, b2));
    a1 = fmaxf(a1, b1);
    if (hi == 0) {
      int row = m0 + (w << 6) + (a << 5) + r32;
      tt2[((size_t)blockIdx.y << 14) + row] =
          make_uint2(__float_as_uint(a1), __float_as_uint(a2));
    }
  }
}

// ---------------- K2: exact fp32 refinement (LDS-staged) + index/histogram ----------------
__global__ __launch_bounds__(256) void refine_kernel(
    const float* __restrict__ z, const float* __restrict__ E,
    const float* __restrict__ zsq, const float* __restrict__ enorm,
    const uint2* __restrict__ tt2, u64* __restrict__ packed,
    float* __restrict__ out_idx, u32* __restrict__ counts) {
  __shared__ uint2 tc[64][33];     // [tile][row-in-block], +pad
  __shared__ float zrow[32][260];  // [pixel][channel], +pad
  const int t = threadIdx.x, w = t >> 6, lane = t & 63;
  const int m0 = blockIdx.x << 5;  // 512 blocks, 32 rows each (same b)
  const int b = m0 >> 10, p0 = m0 & 1023;

  // stage tt2 panel: tile tau, rows m0..m0+31 (coalesced 256B runs)
  #pragma unroll
  for (int i = 0; i < 8; ++i) {
    int tau = (i << 3) + (t >> 5);
    tc[tau][t & 31] = tt2[((size_t)tau << 14) + m0 + (t & 31)];
  }
  // stage z rows via NCHW-coalesced reads -> LDS transpose
  #pragma unroll
  for (int i = 0; i < 8; ++i) {
    int c = (i << 5) + (t >> 3);
    int p4 = (t & 7) << 2;
    float4 v = *(const float4*)&z[((size_t)b << 18) + ((size_t)c << 10) + p0 + p4];
    zrow[p4 + 0][c] = v.x;
    zrow[p4 + 1][c] = v.y;
    zrow[p4 + 2][c] = v.z;
    zrow[p4 + 3][c] = v.w;
  }
  __syncthreads();

  for (int j = 0; j < 8; ++j) {
    const int rr = (w << 3) + j;
    const int m = m0 + rr;
    uint2 c = tc[lane][rr];                       // lane <-> 128-wide tile
    float f0 = __uint_as_float(c.x), f1 = __uint_as_float(c.y);  // f0 >= f1
    float fm = f0;
    #pragma unroll
    for (int off = 1; off < 64; off <<= 1) fm = fmaxf(fm, __shfl_xor(fm, off, 64));
    float thr = fm - 1.5e-4f;                     // margin on (dot+2) scale
    const float4 zr4 = *(const float4*)&zrow[rr][lane << 2];
    float zsqm = zsq[m];
    u64 best = ~0ull;
    #pragma unroll
    for (int s = 0; s < 2; ++s) {
      u32 ck = s ? c.y : c.x;
      float fv = s ? f1 : f0;
      u64 mask = __ballot(fv >= thr);
      while (mask) {
        int src = __ffsll((unsigned long long)mask) - 1;
        mask &= mask - 1;
        u32 key = (u32)__shfl((int)ck, src, 64);
        int idx = (src << 7) | (int)(key & 127u);
        const float4 e4 = *(const float4*)&E[(size_t)idx * CDIM + (lane << 2)];
        float pa = zr4.x * e4.x;                  // identical chain to prior rounds
        pa = fmaf(zr4.y, e4.y, pa);
        pa = fmaf(zr4.z, e4.z, pa);
        pa = fmaf(zr4.w, e4.w, pa);
        #pragma unroll
        for (int off = 1; off < 64; off <<= 1) pa += __shfl_xor(pa, off, 64);
        float ttv = zsqm + enorm[idx];
        float d = ttv - 2.0f * pa;                // exact reference rounding profile
        u64 k2 = ((u64)__float_as_uint(d) << 32) | (u32)idx;
        if (k2 < best) best = k2;                 // lowest-index tie-break
      }
    }
    if (lane == 0) {
      packed[m] = best;
      int idx = (int)(u32)(best & 0xffffffffull);
      out_idx[m] = (float)idx;
      atomicAdd(&counts[idx], 1u);
    }
  }
}

// ---------------- fallback exact fp32 path ----------------
__global__ void enorm_kernel(const float* __restrict__ E, float* __restrict__ enorm) {
  int wave = threadIdx.x >> 6;
  int lane = threadIdx.x & 63;
  int n = blockIdx.x * 4 + wave;
  float4 v = reinterpret_cast<const float4*>(E + (size_t)n * CDIM)[lane];
  float s = v.x * v.x + v.y * v.y + v.z * v.z + v.w * v.w;
  #pragma unroll
  for (int off = 32; off; off >>= 1) s += __shfl_down(s, off, 64);
  if (lane == 0) enorm[n] = s;
}

__global__ void zsq_kernel(const float* __restrict__ z, float* __restrict__ zsq) {
  int blk = blockIdx.x;
  int j = threadIdx.x;
  int b = blk >> 2;
  int p = ((blk & 3) << 8) + j;
  const float* zp = z + (size_t)b * (CDIM * 1024) + p;
  float acc = 0.f;
  #pragma unroll 8
  for (int c = 0; c < CDIM; ++c) {
    float v = zp[(size_t)c * 1024];
    acc += v * v;
  }
  zsq[(blk << 8) + j] = acc;
}

#define BM 128
#define BN 128
#define BK 32
__global__ __launch_bounds__(256, 2) void dist_kernel(
    const float* __restrict__ z, const float* __restrict__ E,
    const float* __restrict__ zsq, const float* __restrict__ enorm,
    unsigned long long* __restrict__ packed) {
  __shared__ float zs[BK][BM];
  __shared__ float es[BK][BN];
  const int t = threadIdx.x;
  const int m0 = blockIdx.x * BM;
  const int n0 = blockIdx.y * BN;
  const int b = m0 >> 10;
  const int p0 = m0 & 1023;
  const int zc = t >> 5;
  const int zm = (t & 31) << 2;
  const float* zbase = z + (size_t)b * 262144 + p0 + zm;
  const int en = t & 127;
  const int ec = (t >> 7) << 4;
  const float* ebase = E + (size_t)(n0 + en) * CDIM + ec;
  float4 zr[4], er[4];
  #pragma unroll
  for (int r = 0; r < 4; ++r)
    zr[r] = *(const float4*)(zbase + (size_t)(r * 8 + zc) * 1024);
  #pragma unroll
  for (int i = 0; i < 4; ++i)
    er[i] = *(const float4*)(ebase + 4 * i);
  float acc[8][8];
  #pragma unroll
  for (int a = 0; a < 8; ++a)
    #pragma unroll
    for (int bb = 0; bb < 8; ++bb) acc[a][bb] = 0.f;
  const int tx = t & 15, ty = t >> 4;
  for (int kt = 0; kt < CDIM / BK; ++kt) {
    __syncthreads();
    #pragma unroll
    for (int r = 0; r < 4; ++r)
      *(float4*)&zs[r * 8 + zc][zm] = zr[r];
    #pragma unroll
    for (int i = 0; i < 4; ++i) {
      es[ec + 4 * i + 0][en] = er[i].x;
      es[ec + 4 * i + 1][en] = er[i].y;
      es[ec + 4 * i + 2][en] = er[i].z;
      es[ec + 4 * i + 3][en] = er[i].w;
    }
    __syncthreads();
    if (kt + 1 < CDIM / BK) {
      const int c0 = (kt + 1) * BK;
      #pragma unroll
      for (int r = 0; r < 4; ++r)
        zr[r] = *(const float4*)(zbase + (size_t)(c0 + r * 8 + zc) * 1024);
      #pragma unroll
      for (int i = 0; i < 4; ++i)
        er[i] = *(const float4*)(ebase + c0 + 4 * i);
    }
    #pragma unroll 8
    for (int kk = 0; kk < BK; ++kk) {
      float4 za = *(const float4*)&zs[kk][ty * 4];
      float4 zb4 = *(const float4*)&zs[kk][64 + ty * 4];
      float4 ea = *(const float4*)&es[kk][tx * 4];
      float4 eb4 = *(const float4*)&es[kk][64 + tx * 4];
      float zv[8] = {za.x, za.y, za.z, za.w, zb4.x, zb4.y, zb4.z, zb4.w};
      float ev[8] = {ea.x, ea.y, ea.z, ea.w, eb4.x, eb4.y, eb4.z, eb4.w};
      #pragma unroll
      for (int a = 0; a < 8; ++a)
        #pragma unroll
        for (int bb = 0; bb < 8; ++bb)
          acc[a][bb] += zv[a] * ev[bb];
    }
  }
  #pragma unroll
  for (int a = 0; a < 8; ++a) {
    int rloc = (a < 4) ? (ty * 4 + a) : (64 + ty * 4 + (a - 4));
    float zq = zsq[m0 + rloc];
    float bestd = 3.4e38f;
    int bestn = 0;
    #pragma unroll
    for (int bb = 0; bb < 8; ++bb) {
      int nloc = (bb < 4) ? (tx * 4 + bb) : (64 + tx * 4 + (bb - 4));
      int n = n0 + nloc;
      float ttv = zq + enorm[n];
      float d = ttv - 2.0f * acc[a][bb];
      if (d < bestd) { bestd = d; bestn = n; }
    }
    unsigned long long pk =
        ((unsigned long long)__float_as_uint(bestd) << 32) | (unsigned)bestn;
    #pragma unroll
    for (int off = 1; off < 16; off <<= 1) {
      unsigned long long other = __shfl_xor(pk, off, 16);
      if (other < pk) pk = other;
    }
    if (tx == 0) atomicMin(&packed[m0 + rloc], pk);
  }
}

__global__ void idx_kernel(const unsigned long long* __restrict__ packed,
                           float* __restrict__ out_idx, unsigned int* __restrict__ counts) {
  int m = blockIdx.x * 256 + threadIdx.x;
  int idx = (int)(unsigned)(packed[m] & 0xffffffffull);
  out_idx[m] = (float)idx;
  atomicAdd(&counts[idx], 1u);
}

// ---------------- gather z_q via LDS transpose, write out (ST), loss partial ----------------
__global__ __launch_bounds__(256) void out_kernel(
    const float* __restrict__ z, const float* __restrict__ E,
    const u64* __restrict__ packed,
    float* __restrict__ out, float* __restrict__ loss_acc) {
  __shared__ float es[32][257];
  const int t = threadIdx.x, w = t >> 6, lane = t & 63;
  const int m0 = blockIdx.x << 5;          // 512 blocks
  const int b = m0 >> 10, p0 = m0 & 1023;

  #pragma unroll
  for (int i = 0; i < 8; ++i) {
    int pl = (w << 3) + i;
    int idx = (int)(u32)(packed[m0 + pl] & 0xffffffffull);
    float4 v = *(const float4*)&E[((size_t)idx << 8) + (lane << 2)];
    es[pl][(lane << 2) + 0] = v.x;
    es[pl][(lane << 2) + 1] = v.y;
    es[pl][(lane << 2) + 2] = v.z;
    es[pl][(lane << 2) + 3] = v.w;
  }
  __syncthreads();

  const int pp = lane & 31, chi = lane >> 5;
  const size_t gbase = ((size_t)b << 18) + p0 + pp;
  float s = 0.f;
  #pragma unroll 8
  for (int i = 0; i < 32; ++i) {
    int c = (i << 3) + (w << 1) + chi;
    float zv = z[gbase + ((size_t)c << 10)];
    float e = es[pp][c];
    float diff = e - zv;
    out[gbase + ((size_t)c << 10)] = zv + diff;
    s = fmaf(diff, diff, s);
  }
  #pragma unroll
  for (int off = 32; off; off >>= 1) s += __shfl_down(s, off, 64);
  __shared__ float red[4];
  if (lane == 0) red[w] = s;
  __syncthreads();
  if (t == 0) atomicAdd(loss_acc, red[0] + red[1] + red[2] + red[3]);
}

__global__ void scalar_kernel(const unsigned int* __restrict__ counts,
                              const float* __restrict__ loss_acc,
                              float* __restrict__ out) {
  float s = 0.f;
  for (int i = threadIdx.x; i < NCODES; i += 256) {
    float pl = (float)counts[i] * (1.0f / 16384.0f);
    s += pl * logf(pl + 1e-10f);
  }
  #pragma unroll
  for (int off = 32; off; off >>= 1) s += __shfl_down(s, off, 64);
  __shared__ float red[4];
  int wv = threadIdx.x >> 6, lane = threadIdx.x & 63;
  if (lane == 0) red[wv] = s;
  __syncthreads();
  if (threadIdx.x == 0) {
    float tot = red[0] + red[1] + red[2] + red[3];
    out[OUT_ELEMS + MTOT] = (1.0f + BETA) * loss_acc[0] * (1.0f / (float)OUT_ELEMS);
    out[OUT_ELEMS + MTOT + 1] = expf(-tot);
  }
}

extern "C" void kernel_launch(void* const* d_in, const int* in_sizes, int n_in,
                              void* d_out, int out_size, void* d_ws, size_t ws_size,
                              hipStream_t stream) {
  const float* z = (const float*)d_in[0];
  const float* E = (const float*)d_in[1];
  float* out = (float*)d_out;
  char* ws = (char*)d_ws;
  u64* packed = (u64*)(ws + WS_PACKED);
  float* enorm = (float*)(ws + WS_ENORM);
  float* zsq = (float*)(ws + WS_ZSQ);
  u32* counts = (u32*)(ws + WS_COUNTS);
  float* loss_acc = (float*)(ws + WS_LOSS);

  hipMemsetAsync(counts, 0, 32768 + 256, stream);  // counts + loss_acc

  if (ws_size >= WS_NEEDED) {
    unsigned short* zb = (unsigned short*)(ws + WS_ZB);
    unsigned short* ebuf = (unsigned short*)(ws + WS_EB);
    uint2* tt2 = (uint2*)(ws + WS_TT2);
    conv_kernel<<<1280, 256, 0, stream>>>(z, E, zb, ebuf, zsq, enorm);
    dim3 g(MTOT / 256, NCODES / 128);
    gemm_kernel<<<g, 256, 0, stream>>>(zb, ebuf, tt2);
    refine_kernel<<<MTOT / 32, 256, 0, stream>>>(z, E, zsq, enorm, tt2, packed,
                                                 out + OUT_ELEMS, counts);
  } else {
    hipMemsetAsync(packed, 0xFF, MTOT * 8, stream);
    enorm_kernel<<<NCODES / 4, 256, 0, stream>>>(E, enorm);
    zsq_kernel<<<64, 256, 0, stream>>>(z, zsq);
    dim3 g(MTOT / BM, NCODES / BN);
    dist_kernel<<<g, 256, 0, stream>>>(z, E, zsq, enorm, packed);
    idx_kernel<<<MTOT / 256, 256, 0, stream>>>(packed, out + OUT_ELEMS, counts);
  }

  out_kernel<<<MTOT / 32, 256, 0, stream>>>(z, E, packed, out, loss_acc);
  scalar_kernel<<<1, 256, 0, stream>>>(counts, loss_acc, out);
}